// Round 9
// baseline (138.330 us; speedup 1.0000x reference)
//
#include <hip/hip_runtime.h>
#include <hip/hip_bf16.h>

// Problem constants
#define BATCH 4
#define DIM 512
#define HEADS 8
#define CH 64          // DIM/HEADS
#define SEQ 2048
#define C3 1536        // 3*DIM
#define L2EPS 1e-12f

typedef float f32x4 __attribute__((ext_vector_type(4)));
typedef short s16x8 __attribute__((ext_vector_type(8)));
typedef unsigned short ushort_t;

// f32 pair -> packed bf16 pair (RNE) — bit version (memory-bound kernels)
static __device__ __forceinline__ unsigned bfpair(float a, float b) {
  unsigned ua = __builtin_bit_cast(unsigned, a);
  unsigned ub = __builtin_bit_cast(unsigned, b);
  ua = (ua + 0x7FFFu + ((ua >> 16) & 1u)) >> 16;
  ub = (ub + 0x7FFFu + ((ub >> 16) & 1u)) >> 16;
  return ua | (ub << 16);
}

// f32 pair -> packed bf16 pair via HW cvt (VALU-critical kernels)
static __device__ __forceinline__ unsigned cvtpk(float lo, float hi) {
  unsigned r;
  asm("v_cvt_pk_bf16_f32 %0, %1, %2" : "=v"(r) : "v"(lo), "v"(hi));
  return r;
}

// single-instruction exp2 (skip OCML's denormal-guard expansion; |x|<=~92 here)
static __device__ __forceinline__ float fexp2(float x) {
  float r;
  asm("v_exp_f32 %0, %1" : "=v"(r) : "v"(x));
  return r;
}

// async global->LDS, 16B per lane; lds dest must be wave-uniform base
static __device__ __forceinline__ void gl_lds16(const void* g, void* l) {
  __builtin_amdgcn_global_load_lds(
      (const __attribute__((address_space(1))) unsigned int*)g,
      (__attribute__((address_space(3))) unsigned int*)l, 16, 0, 0);
}

// ---------------------------------------------------------------------------
// Weight prep: f32 [M][512] -> bf16 [M][512], XOR-swizzled per 64-k chunk.
// ---------------------------------------------------------------------------
__global__ __launch_bounds__(256) void wprep(
    const float* __restrict__ wq, const float* __restrict__ wp,
    unsigned* __restrict__ wqb, unsigned* __restrict__ wpb) {
  const int id = blockIdx.x * 256 + threadIdx.x;
  const float* src;
  unsigned* dst;
  int rid;
  if (id < 1536 * 256) { src = wq; dst = wqb; rid = id; }
  else                 { src = wp; dst = wpb; rid = id - 1536 * 256; }
  const int m = rid >> 8, dcol = rid & 255;
  const int chunk = dcol >> 5, dw = dcol & 31;
  const int sdw = chunk * 32 + (dw ^ (4 * (m & 7)));
  const float* s = src + (size_t)m * 512 + 2 * sdw;
  dst[rid] = bfpair(s[0], s[1]);
}

// ---------------------------------------------------------------------------
// x transpose: f32 x[b][k][n] -> bf16 xbt[b][n][k], swizzled per 64-k chunk.
// ---------------------------------------------------------------------------
__global__ __launch_bounds__(256) void xpose_bf16(
    const float* __restrict__ x, unsigned* __restrict__ xbt) {
  __shared__ unsigned T[64][32];
  const int b = blockIdx.z;
  const int k0 = blockIdx.y * 64;
  const int n0 = blockIdx.x * 64;
  const int nl = threadIdx.x & 63;
  const int dwg = threadIdx.x >> 6;
  const float* xb = x + ((size_t)b * DIM + k0) * SEQ + n0 + nl;
#pragma unroll
  for (int dd = 0; dd < 8; ++dd) {
    const int dw = dwg * 8 + dd;
    const float v0 = xb[(size_t)(2 * dw) * SEQ];
    const float v1 = xb[(size_t)(2 * dw + 1) * SEQ];
    T[nl][dw ^ (4 * (nl & 7))] = bfpair(v0, v1);
  }
  __syncthreads();
#pragma unroll
  for (int rep = 0; rep < 8; ++rep) {
    const int id = rep * 256 + threadIdx.x;
    const int row = id >> 5, dw = id & 31;
    xbt[((size_t)b * SEQ + n0 + row) * 256 + (k0 >> 1) + dw] = T[row][dw];
  }
}

// ---------------------------------------------------------------------------
// bf16 MFMA GEMM: Y[b][m][n] = sum_k W[m][k] * B[b][n][k] + bias[m], K=512.
// ---------------------------------------------------------------------------
__global__ __launch_bounds__(256) void gemm_mfma_bf16(
    const ushort_t* __restrict__ Wb, const ushort_t* __restrict__ Bt,
    const float* __restrict__ bias, float* __restrict__ Y,
    int M, int N) {
  __shared__ __align__(16) char lds[32768];
  char* As = lds;
  char* Bs = lds + 16384;
  const int b = blockIdx.z;
  const int m0 = blockIdx.y * 128, n0 = blockIdx.x * 128;
  const int t = threadIdx.x, w = t >> 6, lane = t & 63;
  const int l15 = lane & 15, g = lane >> 4;
  const int key = 16 * (l15 & 7);
  const int wm = (w >> 1) * 64, wn = (w & 1) * 64;

  const int rsub = lane >> 3;
  const int csub = (lane & 7) * 8;

  f32x4 acc[4][4] = {};

  const ushort_t* Ag0 = Wb + (size_t)(m0 + 32 * w + rsub) * 512 + csub;
  const ushort_t* Bg0 = Bt + ((size_t)b * N + n0 + 32 * w + rsub) * 512 + csub;
  char* Al0 = As + (32 * w) * 128;
  char* Bl0 = Bs + (32 * w) * 128;

  for (int kc = 0; kc < 8; ++kc) {
    const int ko64 = kc * 64;
#pragma unroll
    for (int ri = 0; ri < 4; ++ri) {
      gl_lds16(Ag0 + (size_t)(8 * ri) * 512 + ko64, Al0 + ri * 1024);
      gl_lds16(Bg0 + (size_t)(8 * ri) * 512 + ko64, Bl0 + ri * 1024);
    }
    __syncthreads();
    const char* Abase = As + (wm + l15) * 128;
    const char* Bbase = Bs + (wn + l15) * 128;
#pragma unroll
    for (int ks = 0; ks < 2; ++ks) {
      const int ko = (64 * ks + 16 * g) ^ key;
      s16x8 af[4], bf[4];
#pragma unroll
      for (int mf = 0; mf < 4; ++mf) af[mf] = *(const s16x8*)(Abase + mf * 2048 + ko);
#pragma unroll
      for (int nf = 0; nf < 4; ++nf) bf[nf] = *(const s16x8*)(Bbase + nf * 2048 + ko);
#pragma unroll
      for (int mf = 0; mf < 4; ++mf)
#pragma unroll
        for (int nf = 0; nf < 4; ++nf)
          acc[mf][nf] = __builtin_amdgcn_mfma_f32_16x16x32_bf16(
              af[mf], bf[nf], acc[mf][nf], 0, 0, 0);
    }
    __syncthreads();
  }

#pragma unroll
  for (int mf = 0; mf < 4; ++mf) {
#pragma unroll
    for (int rg = 0; rg < 4; ++rg) {
      const int m = m0 + wm + 16 * mf + 4 * g + rg;
      const float bv = bias[m];
      float* yp = Y + ((size_t)b * M + m) * N + n0 + wn + l15;
#pragma unroll
      for (int nf = 0; nf < 4; ++nf)
        yp[16 * nf] = acc[mf][nf][rg] + bv;
    }
  }
}

// ---------------------------------------------------------------------------
// Depthwise conv k=3 pad=1 + bias. One block per (b,channel) row, 8 n/thread.
// q channels -> f32 qkv + fused qnorm; k -> f32 qkv
// v channels -> bf16 vb tile-major [bh][jt64][cc][32 dwords], dword
//               d ^ 4*(cc&7) swizzle (bank/operand-spread for flash).
// ---------------------------------------------------------------------------
__global__ __launch_bounds__(256) void dwconv2(
    const float* __restrict__ pre, const float* __restrict__ wdw,
    const float* __restrict__ bdw, float* __restrict__ qkv,
    unsigned* __restrict__ vb, float* __restrict__ rq) {
  __shared__ float red[4];
  const int row = blockIdx.x;           // b*1536 + o
  const int o = row % C3;
  const int b = row / C3;
  const int n0 = threadIdx.x * 8;
  const float* src = pre + (size_t)row * SEQ + n0;
  float4 m0 = *(const float4*)src;
  float4 m1 = *(const float4*)(src + 4);
  const float left  = (n0 > 0) ? src[-1] : 0.f;
  const float right = (n0 < SEQ - 8) ? src[8] : 0.f;
  const float w0 = wdw[o * 3 + 0], w1 = wdw[o * 3 + 1], w2 = wdw[o * 3 + 2];
  const float bv = bdw[o];
  const float mid[8] = {m0.x, m0.y, m0.z, m0.w, m1.x, m1.y, m1.z, m1.w};
  const float lf[8]  = {left, m0.x, m0.y, m0.z, m0.w, m1.x, m1.y, m1.z};
  const float rt[8]  = {m0.y, m0.z, m0.w, m1.x, m1.y, m1.z, m1.w, right};
  float y[8];
#pragma unroll
  for (int u = 0; u < 8; ++u) y[u] = w0 * lf[u] + w1 * mid[u] + w2 * rt[u] + bv;

  if (o < 2 * DIM) {
    float* dst = qkv + (size_t)row * SEQ + n0;
    *(float4*)dst = make_float4(y[0], y[1], y[2], y[3]);
    *(float4*)(dst + 4) = make_float4(y[4], y[5], y[6], y[7]);
    if (o < DIM) {  // uniform branch: whole block is one q row
      float s = 0.f;
#pragma unroll
      for (int u = 0; u < 8; ++u) s += y[u] * y[u];
#pragma unroll
      for (int off = 32; off > 0; off >>= 1) s += __shfl_down(s, off);
      if ((threadIdx.x & 63) == 0) red[threadIdx.x >> 6] = s;
      __syncthreads();
      if (threadIdx.x == 0) {
        const float tv = red[0] + red[1] + red[2] + red[3];
        rq[b * DIM + o] = 1.0f / fmaxf(sqrtf(tv), L2EPS);
      }
    }
  } else {
    const int oc = o - 2 * DIM;
    const int h = oc >> 6, cc = oc & 63;
    const int bh = b * 8 + h;
    const int jt = n0 >> 6, d0 = (n0 & 63) >> 1;
    uint4 pk;
    pk.x = bfpair(y[0], y[1]); pk.y = bfpair(y[2], y[3]);
    pk.z = bfpair(y[4], y[5]); pk.w = bfpair(y[6], y[7]);
    *(uint4*)&vb[((size_t)(bh * 32 + jt) * 64 + cc) * 32 +
                 (d0 ^ (4 * (cc & 7)))] = pk;
  }
}

// ---------------------------------------------------------------------------
// k norm over HEAD axis: rk[b][cc][n]
// ---------------------------------------------------------------------------
__global__ __launch_bounds__(256) void knorm_kernel(
    const float* __restrict__ qkv, float* __restrict__ rk) {
  const int idx = blockIdx.x * 256 + threadIdx.x;
  const int n = idx & (SEQ - 1);
  const int cc = (idx >> 11) & 63;
  const int b = idx >> 17;
  const float* base = qkv + ((size_t)b * C3 + DIM + cc) * SEQ + n;
  float s = 0.f;
#pragma unroll
  for (int h = 0; h < HEADS; ++h) {
    float v = base[(size_t)h * CH * SEQ];
    s += v * v;
  }
  rk[idx] = 1.0f / fmaxf(sqrtf(s), L2EPS);
}

// ---------------------------------------------------------------------------
// prep2: coalesced LDS-transpose build of qt / kt.
//  sec0 (qt): rows PERMUTED per 32-row slice — actual row jl goes to slice
//    position 16*((jl>>2)&1) + 4*(jl>>3) + (jl&3). This makes the QK^T
//    C-layout (row m=4g+rg at chunk jf) hold actual j = 32*(jf>>1) + 8g +
//    4*(jf&1) + rg, i.e. exp(st) packed with e=4*(jf&1)+rg is a valid K=32
//    PV B-operand with k == natural j. Rows re-swizzled by DEST row
//    (dw ^ 4*(dr&7)) for bank-spread LDS reads in flash.  *rq applied.
//  sec1 (kt): plain layout, * rk * temp * log2(e).
// ---------------------------------------------------------------------------
__global__ __launch_bounds__(256) void prep2(
    const float* __restrict__ qkv, const float* __restrict__ rq,
    const float* __restrict__ rk, const float* __restrict__ temp,
    unsigned* __restrict__ qt, unsigned* __restrict__ kt) {
  __shared__ unsigned T[64][32];
  const int jt = blockIdx.x, bh = blockIdx.y, sec = blockIdx.z;
  const int b = bh >> 3, h = bh & 7;
  const int jl = threadIdx.x & 63, dwg = threadIdx.x >> 6;
  const int j = jt * 64 + jl;
  if (sec == 0) {
    const float* base = qkv + ((size_t)b * C3 + h * CH) * SEQ + j;
    const float* rqb = rq + b * DIM + h * CH;
#pragma unroll
    for (int dd = 0; dd < 8; ++dd) {
      const int dw = dwg * 8 + dd;
      float v0 = base[(size_t)(2 * dw) * SEQ] * rqb[2 * dw];
      float v1 = base[(size_t)(2 * dw + 1) * SEQ] * rqb[2 * dw + 1];
      T[jl][dw ^ (4 * (jl & 7))] = bfpair(v0, v1);
    }
  } else {
    const float f = temp[h] * 1.44269504f;
    const float* base = qkv + ((size_t)b * C3 + DIM + h * CH) * SEQ + j;
    const float* rkb = rk + (size_t)b * CH * SEQ + j;
#pragma unroll
    for (int dd = 0; dd < 8; ++dd) {
      const int dw = dwg * 8 + dd;
      float v0 = base[(size_t)(2 * dw) * SEQ] * rkb[(size_t)(2 * dw) * SEQ] * f;
      float v1 = base[(size_t)(2 * dw + 1) * SEQ] * rkb[(size_t)(2 * dw + 1) * SEQ] * f;
      T[jl][dw ^ (4 * (jl & 7))] = bfpair(v0, v1);
    }
  }
  __syncthreads();
  unsigned* dst = (sec == 0 ? qt : kt) + ((size_t)bh * SEQ + jt * 64) * 32;
#pragma unroll
  for (int rep = 0; rep < 8; ++rep) {
    const int id = rep * 256 + threadIdx.x;
    const int row = id >> 5, dw = id & 31;
    const unsigned val = T[row][dw ^ (4 * (row & 7))];
    if (sec == 0) {
      const int s = row >> 5, rl = row & 31;
      const int dr = (s << 5) | (16 * ((rl >> 2) & 1) + 4 * (rl >> 3) + (rl & 3));
      dst[dr * 32 + (dw ^ (4 * (dr & 7)))] = val;
    } else {
      dst[row * 32 + dw] = val;
    }
  }
}

// ---------------------------------------------------------------------------
// Flash attention v10 = v7 (R6, proven) with V staging DELETED.
//  R6 ran at ~75 B/cyc LDS — at the ds_read_b128 ceiling. The LDS V path
//  (8KB DMA write + 32KB ds_read per block-tile) is replaced by per-lane
//  direct global 16B loads: the LDS V tile was a LINEAR copy of the vb
//  tile, so the read offset maps 1:1 to a global dword offset
//  (4g+16ks)^(4*(l15&7)) — same bytes, same swizzle, L2-resident.
//  Per-(64i,64j) LDS traffic: 80KB -> 40KB at UNCHANGED occupancy
//  (4 blocks/CU, 1024-block grid). V loads issue at compute() entry,
//  consumed ~400cyc later in PV. Everything else byte-identical to R6.
// ---------------------------------------------------------------------------
__global__ __launch_bounds__(256, 4) void flash_mfma(
    const ushort_t* __restrict__ qt, const ushort_t* __restrict__ kt,
    const unsigned* __restrict__ vb, unsigned* __restrict__ attn_t) {
  __shared__ __align__(16) char lds[16384];
  char* const Q0 = lds;             // [64 pos][128B]
  char* const Q1 = lds + 8192;

  // XCD-aware bijective swizzle: each XCD handles 4 bh values (L2 locality)
  const int orig = blockIdx.y * 32 + blockIdx.x;
  const int swz = (orig & 7) * 128 + (orig >> 3);
  const int bh = swz >> 5, b = bh >> 3, h = bh & 7;
  const int i0 = (swz & 31) * 64;

  const int t = threadIdx.x, w = t >> 6, lane = t & 63;
  const int l15 = lane & 15, g = lane >> 4;
  const int key = 16 * (lane & 7);

  const ushort_t* ktp =
      kt + ((size_t)bh * SEQ + i0 + 16 * w + l15) * 64 + 8 * g;
  const s16x8 kfrag0 = *(const s16x8*)(ktp);
  const s16x8 kfrag1 = *(const s16x8*)(ktp + 32);

  const ushort_t* qtile = qt + (size_t)bh * SEQ * 64;    // + jt*4096

  // V direct-from-global: vb dword index = bh*65536 + jt*2048 + cc*32 + d,
  // cc = 16mf + l15, d = (4g + 16ks) ^ (4*(l15&7)). 16B per load, aligned.
  const unsigned* vlane = vb + (size_t)bh * 65536 + l15 * 32;
  const int vkey = 4 * (l15 & 7);

  // wave-level Q staging: 2 chunks of 1KB (rows 16w..16w+15)
  const int li0 = (w * 2) * 64 + lane;
  const int li1 = li0 + 64;
  const int wo = (w * 2) * 1024;

  f32x4 accO[4] = {};
  float l_run = 0.f;

#define FSTAGE(JT, QD)                                                   \
  do {                                                                   \
    gl_lds16(qtile + (size_t)(JT) * 4096 + li0 * 8, (QD) + wo);          \
    gl_lds16(qtile + (size_t)(JT) * 4096 + li1 * 8, (QD) + wo + 1024);   \
  } while (0)

  auto compute = [&](const char* Qs, int jt) {
    // V fragments: 8 direct 16B global loads, issued before QK^T (no dep)
    const unsigned* vt = vlane + (size_t)jt * 2048;
    s16x8 vf[2][4];
#pragma unroll
    for (int ks = 0; ks < 2; ++ks)
#pragma unroll
      for (int mf = 0; mf < 4; ++mf)
        vf[ks][mf] =
            *(const s16x8*)(vt + mf * 512 + ((4 * g + 16 * ks) ^ vkey));

    f32x4 st[4];
    __builtin_amdgcn_s_setprio(1);
#pragma unroll
    for (int jf = 0; jf < 4; ++jf) {
      const char* qrow = Qs + (16 * jf + l15) * 128;
      s16x8 a0 = *(const s16x8*)(qrow + ((16 * g) ^ key));
      s16x8 a1 = *(const s16x8*)(qrow + ((16 * g + 64) ^ key));
      f32x4 z = {};
      z = __builtin_amdgcn_mfma_f32_16x16x32_bf16(a0, kfrag0, z, 0, 0, 0);
      z = __builtin_amdgcn_mfma_f32_16x16x32_bf16(a1, kfrag1, z, 0, 0, 0);
      st[jf] = z;
    }
    __builtin_amdgcn_s_setprio(0);

    // P = exp2(st) in regs; permuted qt makes pb a valid K=32 B-operand
    s16x8 pb[2];
#pragma unroll
    for (int ks = 0; ks < 2; ++ks) {
      const float e0 = fexp2(st[2 * ks][0]);
      const float e1 = fexp2(st[2 * ks][1]);
      const float e2 = fexp2(st[2 * ks][2]);
      const float e3 = fexp2(st[2 * ks][3]);
      const float e4 = fexp2(st[2 * ks + 1][0]);
      const float e5 = fexp2(st[2 * ks + 1][1]);
      const float e6 = fexp2(st[2 * ks + 1][2]);
      const float e7 = fexp2(st[2 * ks + 1][3]);
      l_run += ((e0 + e1) + (e2 + e3)) + ((e4 + e5) + (e6 + e7));
      uint4 u;
      u.x = cvtpk(e0, e1);
      u.y = cvtpk(e2, e3);
      u.z = cvtpk(e4, e5);
      u.w = cvtpk(e6, e7);
      pb[ks] = __builtin_bit_cast(s16x8, u);
    }

    __builtin_amdgcn_s_setprio(1);
#pragma unroll
    for (int ks = 0; ks < 2; ++ks)
#pragma unroll
      for (int mf = 0; mf < 4; ++mf)
        accO[mf] = __builtin_amdgcn_mfma_f32_16x16x32_bf16(
            vf[ks][mf], pb[ks], accO[mf], 0, 0, 0);
    __builtin_amdgcn_s_setprio(0);
  };

  FSTAGE(0, Q0);
  __syncthreads();
#pragma unroll 1
  for (int jt2 = 0; jt2 < 16; ++jt2) {
    const int jt = 2 * jt2;
    FSTAGE(jt + 1, Q1);              // overlaps with compute below
    compute(Q0, jt);
    __syncthreads();                 // drain: Q1 now ready
    if (jt2 < 15) FSTAGE(jt + 2, Q0);
    compute(Q1, jt + 1);
    __syncthreads();
  }

  // ---- deferred l reduction over the 4 j-row-groups ----
  l_run += __shfl_xor(l_run, 16);
  l_run += __shfl_xor(l_run, 32);
  const float inv = 1.0f / l_run;

  // ---- epilogue: bf16 attn_t, swizzled k-major [b][i][c] ----
  unsigned* Pw = (unsigned*)(lds + w * 2048);  // Q region, now free
  const int kk = 4 * (l15 & 7);
#pragma unroll
  for (int mf = 0; mf < 4; ++mf) {
    uint2 pk;
    pk.x = cvtpk(accO[mf][0] * inv, accO[mf][1] * inv);
    pk.y = cvtpk(accO[mf][2] * inv, accO[mf][3] * inv);
    const int dwb = 8 * mf + 2 * g;
    *(uint2*)&Pw[l15 * 32 + (dwb ^ kk)] = pk;
  }
  __syncthreads();
#pragma unroll
  for (int rep = 0; rep < 8; ++rep) {
    const int id = rep * 64 + lane;
    const int row = id >> 5, dw = id & 31;
    attn_t[((size_t)b * SEQ + i0 + 16 * w + row) * 256 + h * 32 + dw] =
        Pw[row * 32 + dw];
  }
#undef FSTAGE
}

// ---------------------------------------------------------------------------
extern "C" void kernel_launch(void* const* d_in, const int* in_sizes, int n_in,
                              void* d_out, int out_size, void* d_ws, size_t ws_size,
                              hipStream_t stream) {
  const float* x      = (const float*)d_in[0];
  const float* w_qkv  = (const float*)d_in[1];
  const float* b_qkv  = (const float*)d_in[2];
  const float* w_dw   = (const float*)d_in[3];
  const float* b_dw   = (const float*)d_in[4];
  const float* w_po   = (const float*)d_in[5];
  const float* b_po   = (const float*)d_in[6];
  const float* temp   = (const float*)d_in[7];
  float* out = (float*)d_out;
  float* ws  = (float*)d_ws;

  // workspace layout (float units)
  float* qkv_pre = ws;                            // 12,582,912 floats
  float* qkv     = ws + 12582912;                 // 12,582,912 floats (q,k used)
  float* rq      = ws + 25165824;                 // 2048
  float* rk      = ws + 25167872;                 // 524,288
  unsigned* xbt  = (unsigned*)(ws + 25692160);    // 2M dwords (8MB)
  unsigned* wqb  = (unsigned*)(ws + 27789312);    // 384K dwords
  unsigned* wpb  = (unsigned*)(ws + 28182528);    // 128K dwords
  // xbt region reused after QKV GEMM:
  unsigned* vb     = (unsigned*)(ws + 25692160);  // 2M dwords (dwconv2 output)
  // qkv_pre region reused after dwconv2:
  unsigned* qt     = (unsigned*)(ws);             // 2M dwords
  unsigned* kt     = (unsigned*)(ws + 2097152);   // 2M dwords
  unsigned* attn_t = (unsigned*)(ws + 4194304);   // 2M dwords

  // 0) bf16 conversions
  wprep<<<2048, 256, 0, stream>>>(w_qkv, w_po, wqb, wpb);
  xpose_bf16<<<dim3(SEQ / 64, DIM / 64, BATCH), 256, 0, stream>>>(x, xbt);

  // 1) QKV pointwise conv (bf16 MFMA)
  gemm_mfma_bf16<<<dim3(SEQ / 128, C3 / 128, BATCH), 256, 0, stream>>>(
      (const ushort_t*)wqb, (const ushort_t*)xbt, b_qkv, qkv_pre, C3, SEQ);

  // 2) depthwise conv; v -> bf16 vb directly, q/k -> f32 qkv; qnorm fused
  dwconv2<<<BATCH * C3, 256, 0, stream>>>(qkv_pre, w_dw, b_dw, qkv, vb, rq);

  // 3) k norm (q norm fused into dwconv2)
  knorm_kernel<<<(BATCH * CH * SEQ) / 256, 256, 0, stream>>>(qkv, rk);

  // 4) bf16 prep of qt / kt (coalesced transpose; qt rows permuted+swizzled)
  prep2<<<dim3(32, BATCH * HEADS, 2), 256, 0, stream>>>(
      qkv, rq, rk, temp, qt, kt);

  // 5) MFMA flash attention -> bf16 attn_t
  flash_mfma<<<dim3(SEQ / 64, BATCH * HEADS), 256, 0, stream>>>(
      (const ushort_t*)qt, (const ushort_t*)kt, (const unsigned*)vb, attn_t);

  // 6) output pointwise conv (bf16 MFMA)
  gemm_mfma_bf16<<<dim3(SEQ / 128, DIM / 128, BATCH), 256, 0, stream>>>(
      (const ushort_t*)wpb, (const ushort_t*)attn_t, b_po, out, DIM, SEQ);
}

// Round 10
// 111.489 us; speedup vs baseline: 1.2407x; 1.2407x over previous
//
#include <hip/hip_runtime.h>
#include <hip/hip_bf16.h>

// Problem constants
#define BATCH 4
#define DIM 512
#define HEADS 8
#define CH 64          // DIM/HEADS
#define SEQ 2048
#define C3 1536        // 3*DIM
#define L2EPS 1e-12f

typedef float f32x4 __attribute__((ext_vector_type(4)));
typedef short s16x8 __attribute__((ext_vector_type(8)));
typedef unsigned short ushort_t;

// f32 pair -> packed bf16 pair (RNE) — bit version (memory-bound kernels)
static __device__ __forceinline__ unsigned bfpair(float a, float b) {
  unsigned ua = __builtin_bit_cast(unsigned, a);
  unsigned ub = __builtin_bit_cast(unsigned, b);
  ua = (ua + 0x7FFFu + ((ua >> 16) & 1u)) >> 16;
  ub = (ub + 0x7FFFu + ((ub >> 16) & 1u)) >> 16;
  return ua | (ub << 16);
}

// single f32 -> bf16 (RNE)
static __device__ __forceinline__ ushort_t bf16r(float a) {
  unsigned u = __builtin_bit_cast(unsigned, a);
  u = (u + 0x7FFFu + ((u >> 16) & 1u)) >> 16;
  return (ushort_t)u;
}

// bf16 -> f32
static __device__ __forceinline__ float bf2f(ushort_t u) {
  return __builtin_bit_cast(float, ((unsigned)u) << 16);
}

// f32 pair -> packed bf16 pair via HW cvt (VALU-critical kernels)
static __device__ __forceinline__ unsigned cvtpk(float lo, float hi) {
  unsigned r;
  asm("v_cvt_pk_bf16_f32 %0, %1, %2" : "=v"(r) : "v"(lo), "v"(hi));
  return r;
}

// single-instruction exp2 (skip OCML's denormal-guard expansion; |x|<=~92 here)
static __device__ __forceinline__ float fexp2(float x) {
  float r;
  asm("v_exp_f32 %0, %1" : "=v"(r) : "v"(x));
  return r;
}

// async global->LDS, 16B per lane; lds dest must be wave-uniform base
static __device__ __forceinline__ void gl_lds16(const void* g, void* l) {
  __builtin_amdgcn_global_load_lds(
      (const __attribute__((address_space(1))) unsigned int*)g,
      (__attribute__((address_space(3))) unsigned int*)l, 16, 0, 0);
}

// ---------------------------------------------------------------------------
// Weight prep: f32 [M][512] -> bf16 [M][512], XOR-swizzled per 64-k chunk.
// ---------------------------------------------------------------------------
__global__ __launch_bounds__(256) void wprep(
    const float* __restrict__ wq, const float* __restrict__ wp,
    unsigned* __restrict__ wqb, unsigned* __restrict__ wpb) {
  const int id = blockIdx.x * 256 + threadIdx.x;
  const float* src;
  unsigned* dst;
  int rid;
  if (id < 1536 * 256) { src = wq; dst = wqb; rid = id; }
  else                 { src = wp; dst = wpb; rid = id - 1536 * 256; }
  const int m = rid >> 8, dcol = rid & 255;
  const int chunk = dcol >> 5, dw = dcol & 31;
  const int sdw = chunk * 32 + (dw ^ (4 * (m & 7)));
  const float* s = src + (size_t)m * 512 + 2 * sdw;
  dst[rid] = bfpair(s[0], s[1]);
}

// ---------------------------------------------------------------------------
// x transpose: f32 x[b][k][n] -> bf16 xbt[b][n][k], swizzled per 64-k chunk.
// ---------------------------------------------------------------------------
__global__ __launch_bounds__(256) void xpose_bf16(
    const float* __restrict__ x, unsigned* __restrict__ xbt) {
  __shared__ unsigned T[64][32];
  const int b = blockIdx.z;
  const int k0 = blockIdx.y * 64;
  const int n0 = blockIdx.x * 64;
  const int nl = threadIdx.x & 63;
  const int dwg = threadIdx.x >> 6;
  const float* xb = x + ((size_t)b * DIM + k0) * SEQ + n0 + nl;
#pragma unroll
  for (int dd = 0; dd < 8; ++dd) {
    const int dw = dwg * 8 + dd;
    const float v0 = xb[(size_t)(2 * dw) * SEQ];
    const float v1 = xb[(size_t)(2 * dw + 1) * SEQ];
    T[nl][dw ^ (4 * (nl & 7))] = bfpair(v0, v1);
  }
  __syncthreads();
#pragma unroll
  for (int rep = 0; rep < 8; ++rep) {
    const int id = rep * 256 + threadIdx.x;
    const int row = id >> 5, dw = id & 31;
    xbt[((size_t)b * SEQ + n0 + row) * 256 + (k0 >> 1) + dw] = T[row][dw];
  }
}

// ---------------------------------------------------------------------------
// bf16 MFMA GEMM: Y[b][m][n] = sum_k W[m][k] * B[b][n][k] + bias[m], K=512.
// OBF=true: store bf16 (halves HBM write traffic for the qkv_pre intermediate)
// ---------------------------------------------------------------------------
template <bool OBF>
__global__ __launch_bounds__(256) void gemm_mfma_bf16(
    const ushort_t* __restrict__ Wb, const ushort_t* __restrict__ Bt,
    const float* __restrict__ bias, float* __restrict__ Y,
    int M, int N) {
  __shared__ __align__(16) char lds[32768];
  char* As = lds;
  char* Bs = lds + 16384;
  const int b = blockIdx.z;
  const int m0 = blockIdx.y * 128, n0 = blockIdx.x * 128;
  const int t = threadIdx.x, w = t >> 6, lane = t & 63;
  const int l15 = lane & 15, g = lane >> 4;
  const int key = 16 * (l15 & 7);
  const int wm = (w >> 1) * 64, wn = (w & 1) * 64;

  const int rsub = lane >> 3;
  const int csub = (lane & 7) * 8;

  f32x4 acc[4][4] = {};

  const ushort_t* Ag0 = Wb + (size_t)(m0 + 32 * w + rsub) * 512 + csub;
  const ushort_t* Bg0 = Bt + ((size_t)b * N + n0 + 32 * w + rsub) * 512 + csub;
  char* Al0 = As + (32 * w) * 128;
  char* Bl0 = Bs + (32 * w) * 128;

  for (int kc = 0; kc < 8; ++kc) {
    const int ko64 = kc * 64;
#pragma unroll
    for (int ri = 0; ri < 4; ++ri) {
      gl_lds16(Ag0 + (size_t)(8 * ri) * 512 + ko64, Al0 + ri * 1024);
      gl_lds16(Bg0 + (size_t)(8 * ri) * 512 + ko64, Bl0 + ri * 1024);
    }
    __syncthreads();
    const char* Abase = As + (wm + l15) * 128;
    const char* Bbase = Bs + (wn + l15) * 128;
#pragma unroll
    for (int ks = 0; ks < 2; ++ks) {
      const int ko = (64 * ks + 16 * g) ^ key;
      s16x8 af[4], bf[4];
#pragma unroll
      for (int mf = 0; mf < 4; ++mf) af[mf] = *(const s16x8*)(Abase + mf * 2048 + ko);
#pragma unroll
      for (int nf = 0; nf < 4; ++nf) bf[nf] = *(const s16x8*)(Bbase + nf * 2048 + ko);
#pragma unroll
      for (int mf = 0; mf < 4; ++mf)
#pragma unroll
        for (int nf = 0; nf < 4; ++nf)
          acc[mf][nf] = __builtin_amdgcn_mfma_f32_16x16x32_bf16(
              af[mf], bf[nf], acc[mf][nf], 0, 0, 0);
    }
    __syncthreads();
  }

#pragma unroll
  for (int mf = 0; mf < 4; ++mf) {
#pragma unroll
    for (int rg = 0; rg < 4; ++rg) {
      const int m = m0 + wm + 16 * mf + 4 * g + rg;
      const float bv = bias[m];
      if constexpr (OBF) {
        ushort_t* yp =
            (ushort_t*)Y + ((size_t)b * M + m) * N + n0 + wn + l15;
#pragma unroll
        for (int nf = 0; nf < 4; ++nf)
          yp[16 * nf] = bf16r(acc[mf][nf][rg] + bv);
      } else {
        float* yp = Y + ((size_t)b * M + m) * N + n0 + wn + l15;
#pragma unroll
        for (int nf = 0; nf < 4; ++nf)
          yp[16 * nf] = acc[mf][nf][rg] + bv;
      }
    }
  }
}

// ---------------------------------------------------------------------------
// Depthwise conv k=3 pad=1 + bias. One block per (b,channel) row, 8 n/thread.
// bf16 input (qkv_pre); q/k -> bf16 qkv + fused qnorm (f32); v -> bf16 vb
// tile-major [bh][jt64][cc][32 dwords], dword d ^ 4*(cc&7) swizzle.
// ---------------------------------------------------------------------------
__global__ __launch_bounds__(256) void dwconv2(
    const ushort_t* __restrict__ pre, const float* __restrict__ wdw,
    const float* __restrict__ bdw, ushort_t* __restrict__ qkv,
    unsigned* __restrict__ vb, float* __restrict__ rq) {
  __shared__ float red[4];
  const int row = blockIdx.x;           // b*1536 + o
  const int o = row % C3;
  const int b = row / C3;
  const int n0 = threadIdx.x * 8;
  const ushort_t* src = pre + (size_t)row * SEQ + n0;
  const s16x8 mv = *(const s16x8*)src;
  const float left  = (n0 > 0) ? bf2f(src[-1]) : 0.f;
  const float right = (n0 < SEQ - 8) ? bf2f(src[8]) : 0.f;
  const float w0 = wdw[o * 3 + 0], w1 = wdw[o * 3 + 1], w2 = wdw[o * 3 + 2];
  const float bv = bdw[o];
  float mid[8];
#pragma unroll
  for (int u = 0; u < 8; ++u) mid[u] = bf2f((ushort_t)mv[u]);
  const float lf[8] = {left,   mid[0], mid[1], mid[2],
                       mid[3], mid[4], mid[5], mid[6]};
  const float rt[8] = {mid[1], mid[2], mid[3], mid[4],
                       mid[5], mid[6], mid[7], right};
  float y[8];
#pragma unroll
  for (int u = 0; u < 8; ++u) y[u] = w0 * lf[u] + w1 * mid[u] + w2 * rt[u] + bv;

  if (o < 2 * DIM) {
    uint4 pk;
    pk.x = bfpair(y[0], y[1]); pk.y = bfpair(y[2], y[3]);
    pk.z = bfpair(y[4], y[5]); pk.w = bfpair(y[6], y[7]);
    *(uint4*)(qkv + (size_t)row * SEQ + n0) = pk;
    if (o < DIM) {  // uniform branch: whole block is one q row
      float s = 0.f;
#pragma unroll
      for (int u = 0; u < 8; ++u) s += y[u] * y[u];
#pragma unroll
      for (int off = 32; off > 0; off >>= 1) s += __shfl_down(s, off);
      if ((threadIdx.x & 63) == 0) red[threadIdx.x >> 6] = s;
      __syncthreads();
      if (threadIdx.x == 0) {
        const float tv = red[0] + red[1] + red[2] + red[3];
        rq[b * DIM + o] = 1.0f / fmaxf(sqrtf(tv), L2EPS);
      }
    }
  } else {
    const int oc = o - 2 * DIM;
    const int h = oc >> 6, cc = oc & 63;
    const int bh = b * 8 + h;
    const int jt = n0 >> 6, d0 = (n0 & 63) >> 1;
    uint4 pk;
    pk.x = bfpair(y[0], y[1]); pk.y = bfpair(y[2], y[3]);
    pk.z = bfpair(y[4], y[5]); pk.w = bfpair(y[6], y[7]);
    *(uint4*)&vb[((size_t)(bh * 32 + jt) * 64 + cc) * 32 +
                 (d0 ^ (4 * (cc & 7)))] = pk;
  }
}

// ---------------------------------------------------------------------------
// k norm over HEAD axis: rk[b][cc][n]  (bf16 input)
// ---------------------------------------------------------------------------
__global__ __launch_bounds__(256) void knorm_kernel(
    const ushort_t* __restrict__ qkv, float* __restrict__ rk) {
  const int idx = blockIdx.x * 256 + threadIdx.x;
  const int n = idx & (SEQ - 1);
  const int cc = (idx >> 11) & 63;
  const int b = idx >> 17;
  const ushort_t* base = qkv + ((size_t)b * C3 + DIM + cc) * SEQ + n;
  float s = 0.f;
#pragma unroll
  for (int h = 0; h < HEADS; ++h) {
    float v = bf2f(base[(size_t)h * CH * SEQ]);
    s += v * v;
  }
  rk[idx] = 1.0f / fmaxf(sqrtf(s), L2EPS);
}

// ---------------------------------------------------------------------------
// prep2: coalesced LDS-transpose build of qt / kt (bf16 input).
//  sec0 (qt): rows PERMUTED per 32-row slice — actual row jl goes to slice
//    position 16*((jl>>2)&1) + 4*(jl>>3) + (jl&3). This makes the QK^T
//    C-layout (row m=4g+rg at chunk jf) hold actual j = 32*(jf>>1) + 8g +
//    4*(jf&1) + rg, i.e. exp(st) packed with e=4*(jf&1)+rg is a valid K=32
//    PV B-operand with k == natural j. Rows re-swizzled by DEST row
//    (dw ^ 4*(dr&7)) for bank-spread LDS reads in flash.  *rq applied.
//  sec1 (kt): plain layout, * rk * temp * log2(e).
// ---------------------------------------------------------------------------
__global__ __launch_bounds__(256) void prep2(
    const ushort_t* __restrict__ qkv, const float* __restrict__ rq,
    const float* __restrict__ rk, const float* __restrict__ temp,
    unsigned* __restrict__ qt, unsigned* __restrict__ kt) {
  __shared__ unsigned T[64][32];
  const int jt = blockIdx.x, bh = blockIdx.y, sec = blockIdx.z;
  const int b = bh >> 3, h = bh & 7;
  const int jl = threadIdx.x & 63, dwg = threadIdx.x >> 6;
  const int j = jt * 64 + jl;
  if (sec == 0) {
    const ushort_t* base = qkv + ((size_t)b * C3 + h * CH) * SEQ + j;
    const float* rqb = rq + b * DIM + h * CH;
#pragma unroll
    for (int dd = 0; dd < 8; ++dd) {
      const int dw = dwg * 8 + dd;
      float v0 = bf2f(base[(size_t)(2 * dw) * SEQ]) * rqb[2 * dw];
      float v1 = bf2f(base[(size_t)(2 * dw + 1) * SEQ]) * rqb[2 * dw + 1];
      T[jl][dw ^ (4 * (jl & 7))] = bfpair(v0, v1);
    }
  } else {
    const float f = temp[h] * 1.44269504f;
    const ushort_t* base = qkv + ((size_t)b * C3 + DIM + h * CH) * SEQ + j;
    const float* rkb = rk + (size_t)b * CH * SEQ + j;
#pragma unroll
    for (int dd = 0; dd < 8; ++dd) {
      const int dw = dwg * 8 + dd;
      float v0 = bf2f(base[(size_t)(2 * dw) * SEQ]) *
                 rkb[(size_t)(2 * dw) * SEQ] * f;
      float v1 = bf2f(base[(size_t)(2 * dw + 1) * SEQ]) *
                 rkb[(size_t)(2 * dw + 1) * SEQ] * f;
      T[jl][dw ^ (4 * (jl & 7))] = bfpair(v0, v1);
    }
  }
  __syncthreads();
  unsigned* dst = (sec == 0 ? qt : kt) + ((size_t)bh * SEQ + jt * 64) * 32;
#pragma unroll
  for (int rep = 0; rep < 8; ++rep) {
    const int id = rep * 256 + threadIdx.x;
    const int row = id >> 5, dw = id & 31;
    const unsigned val = T[row][dw ^ (4 * (row & 7))];
    if (sec == 0) {
      const int s = row >> 5, rl = row & 31;
      const int dr = (s << 5) | (16 * ((rl >> 2) & 1) + 4 * (rl >> 3) + (rl & 3));
      dst[dr * 32 + (dw ^ (4 * (dr & 7)))] = val;
    } else {
      dst[row * 32 + dw] = val;
    }
  }
}

// ---------------------------------------------------------------------------
// Flash attention v8 (R7, best measured): 32-i wave strips, 128-i blocks.
//  Q/V staged in LDS (shared by 4 waves), double-buffered, 1 barrier/tile.
//  P stays in registers via the qt row permutation (QK^T C == K=32 PV B).
// ---------------------------------------------------------------------------
__global__ __launch_bounds__(256, 2) void flash_mfma(
    const ushort_t* __restrict__ qt, const ushort_t* __restrict__ kt,
    const ushort_t* __restrict__ vb, unsigned* __restrict__ attn_t) {
  __shared__ __align__(16) char lds[32768];
  char* const Q0 = lds;             // [64 pos][128B]
  char* const Q1 = lds + 8192;
  char* const V0 = lds + 16384;     // [64 cc][128B]
  char* const V1 = lds + 24576;

  // XCD-aware bijective swizzle over 512 blocks: 64 per XCD = 4 bh values
  const int orig = blockIdx.y * 16 + blockIdx.x;
  const int swz = (orig & 7) * 64 + (orig >> 3);
  const int bh = swz >> 4, b = bh >> 3, h = bh & 7;
  const int i0 = (swz & 15) * 128;

  const int t = threadIdx.x, w = t >> 6, lane = t & 63;
  const int l15 = lane & 15, g = lane >> 4;
  const int key = 16 * (lane & 7);

  // K fragments for the wave's two 16-i blocks: 32 VGPR
  const ushort_t* ktp =
      kt + ((size_t)bh * SEQ + i0 + 32 * w + l15) * 64 + 8 * g;
  s16x8 kf0[2], kf1[2];
#pragma unroll
  for (int ib = 0; ib < 2; ++ib) {
    kf0[ib] = *(const s16x8*)(ktp + ib * 1024);
    kf1[ib] = *(const s16x8*)(ktp + ib * 1024 + 32);
  }

  const ushort_t* qtile = qt + (size_t)bh * SEQ * 64;    // + jt*4096
  const ushort_t* vtile = vb + (size_t)bh * 32 * 4096;   // + jt*4096

  // wave-level staging: 2 chunks of 1KB each for Q and V
  const int li0 = (w * 2) * 64 + lane;
  const int li1 = li0 + 64;
  const int wo = (w * 2) * 1024;

  f32x4 accO[4][2] = {};   // [mf(cc)][ib]
  float lr[2] = {};

#define FSTAGE(JT, QD, VD)                                               \
  do {                                                                   \
    gl_lds16(qtile + (size_t)(JT) * 4096 + li0 * 8, (QD) + wo);          \
    gl_lds16(qtile + (size_t)(JT) * 4096 + li1 * 8, (QD) + wo + 1024);   \
    gl_lds16(vtile + (size_t)(JT) * 4096 + li0 * 8, (VD) + wo);          \
    gl_lds16(vtile + (size_t)(JT) * 4096 + li1 * 8, (VD) + wo + 1024);   \
  } while (0)

  auto compute = [&](const char* Qs, const char* Vs) {
    f32x4 st[4][2];
    __builtin_amdgcn_s_setprio(1);
#pragma unroll
    for (int jf = 0; jf < 4; ++jf) {
      const char* qrow = Qs + (16 * jf + l15) * 128;
      s16x8 a0 = *(const s16x8*)(qrow + ((16 * g) ^ key));
      s16x8 a1 = *(const s16x8*)(qrow + ((16 * g + 64) ^ key));
#pragma unroll
      for (int ib = 0; ib < 2; ++ib) {
        f32x4 z = {};
        z = __builtin_amdgcn_mfma_f32_16x16x32_bf16(a0, kf0[ib], z, 0, 0, 0);
        z = __builtin_amdgcn_mfma_f32_16x16x32_bf16(a1, kf1[ib], z, 0, 0, 0);
        st[jf][ib] = z;
      }
    }
    __builtin_amdgcn_s_setprio(0);

    // P = exp2(st) in regs; permuted qt makes pb a valid K=32 B-operand
    s16x8 pb[2][2];
#pragma unroll
    for (int ib = 0; ib < 2; ++ib)
#pragma unroll
      for (int ks = 0; ks < 2; ++ks) {
        const float e0 = fexp2(st[2 * ks][ib][0]);
        const float e1 = fexp2(st[2 * ks][ib][1]);
        const float e2 = fexp2(st[2 * ks][ib][2]);
        const float e3 = fexp2(st[2 * ks][ib][3]);
        const float e4 = fexp2(st[2 * ks + 1][ib][0]);
        const float e5 = fexp2(st[2 * ks + 1][ib][1]);
        const float e6 = fexp2(st[2 * ks + 1][ib][2]);
        const float e7 = fexp2(st[2 * ks + 1][ib][3]);
        lr[ib] += ((e0 + e1) + (e2 + e3)) + ((e4 + e5) + (e6 + e7));
        uint4 u;
        u.x = cvtpk(e0, e1);
        u.y = cvtpk(e2, e3);
        u.z = cvtpk(e4, e5);
        u.w = cvtpk(e6, e7);
        pb[ib][ks] = __builtin_bit_cast(s16x8, u);
      }

    __builtin_amdgcn_s_setprio(1);
#pragma unroll
    for (int ks = 0; ks < 2; ++ks)
#pragma unroll
      for (int mf = 0; mf < 4; ++mf) {
        const char* vrow = Vs + (16 * mf + l15) * 128;
        s16x8 aV = *(const s16x8*)(vrow + ((16 * g + 64 * ks) ^ key));
#pragma unroll
        for (int ib = 0; ib < 2; ++ib)
          accO[mf][ib] = __builtin_amdgcn_mfma_f32_16x16x32_bf16(
              aV, pb[ib][ks], accO[mf][ib], 0, 0, 0);
      }
    __builtin_amdgcn_s_setprio(0);
  };

  FSTAGE(0, Q0, V0);
  __syncthreads();
#pragma unroll 1
  for (int jt2 = 0; jt2 < 16; ++jt2) {
    const int jt = 2 * jt2;
    FSTAGE(jt + 1, Q1, V1);          // overlaps with compute below
    compute(Q0, V0);
    __syncthreads();                 // vmcnt(0) drain: Q1/V1 now ready
    if (jt2 < 15) FSTAGE(jt + 2, Q0, V0);
    compute(Q1, V1);
    __syncthreads();
  }

  // ---- deferred l reduction over the 4 j-row-groups ----
  float inv[2];
#pragma unroll
  for (int ib = 0; ib < 2; ++ib) {
    lr[ib] += __shfl_xor(lr[ib], 16);
    lr[ib] += __shfl_xor(lr[ib], 32);
    inv[ib] = 1.0f / lr[ib];
  }

  // ---- epilogue: bf16 attn_t, swizzled k-major [b][i][c] ----
  unsigned* Pw = (unsigned*)(lds + w * 4096);  // 32 rows x 128B per wave
  const int kk = 4 * (l15 & 7);
#pragma unroll
  for (int ib = 0; ib < 2; ++ib)
#pragma unroll
    for (int mf = 0; mf < 4; ++mf) {
      uint2 pk;
      pk.x = cvtpk(accO[mf][ib][0] * inv[ib], accO[mf][ib][1] * inv[ib]);
      pk.y = cvtpk(accO[mf][ib][2] * inv[ib], accO[mf][ib][3] * inv[ib]);
      const int dwb = 8 * mf + 2 * g;
      *(uint2*)&Pw[(16 * ib + l15) * 32 + (dwb ^ kk)] = pk;
    }
  __syncthreads();
#pragma unroll
  for (int rep = 0; rep < 16; ++rep) {
    const int id = rep * 64 + lane;
    const int row = id >> 5, dw = id & 31;
    attn_t[((size_t)b * SEQ + i0 + 32 * w + row) * 256 + h * 32 + dw] =
        Pw[row * 32 + dw];
  }
#undef FSTAGE
}

// ---------------------------------------------------------------------------
extern "C" void kernel_launch(void* const* d_in, const int* in_sizes, int n_in,
                              void* d_out, int out_size, void* d_ws, size_t ws_size,
                              hipStream_t stream) {
  const float* x      = (const float*)d_in[0];
  const float* w_qkv  = (const float*)d_in[1];
  const float* b_qkv  = (const float*)d_in[2];
  const float* w_dw   = (const float*)d_in[3];
  const float* b_dw   = (const float*)d_in[4];
  const float* w_po   = (const float*)d_in[5];
  const float* b_po   = (const float*)d_in[6];
  const float* temp   = (const float*)d_in[7];
  float* out = (float*)d_out;
  float* ws  = (float*)d_ws;

  // workspace layout (float units; qkv_pre/qkv now bf16 inside their regions)
  ushort_t* qkv_pre_b = (ushort_t*)ws;            // 12.58M bf16 (fits region)
  ushort_t* qkvb = (ushort_t*)(ws + 12582912);    // 12.58M bf16 (q,k used)
  float* rq      = ws + 25165824;                 // 2048
  float* rk      = ws + 25167872;                 // 524,288
  unsigned* xbt  = (unsigned*)(ws + 25692160);    // 2M dwords (8MB)
  unsigned* wqb  = (unsigned*)(ws + 27789312);    // 384K dwords
  unsigned* wpb  = (unsigned*)(ws + 28182528);    // 128K dwords
  // xbt region reused after QKV GEMM:
  unsigned* vb     = (unsigned*)(ws + 25692160);  // 2M dwords (dwconv2 output)
  // qkv_pre region reused after dwconv2:
  unsigned* qt     = (unsigned*)(ws);             // 2M dwords
  unsigned* kt     = (unsigned*)(ws + 2097152);   // 2M dwords
  unsigned* attn_t = (unsigned*)(ws + 4194304);   // 2M dwords

  // 0) bf16 conversions
  wprep<<<2048, 256, 0, stream>>>(w_qkv, w_po, wqb, wpb);
  xpose_bf16<<<dim3(SEQ / 64, DIM / 64, BATCH), 256, 0, stream>>>(x, xbt);

  // 1) QKV pointwise conv (bf16 MFMA) -> bf16 qkv_pre
  gemm_mfma_bf16<true><<<dim3(SEQ / 128, C3 / 128, BATCH), 256, 0, stream>>>(
      (const ushort_t*)wqb, (const ushort_t*)xbt, b_qkv,
      (float*)qkv_pre_b, C3, SEQ);

  // 2) depthwise conv (bf16 in); v -> bf16 vb, q/k -> bf16 qkv; qnorm fused
  dwconv2<<<BATCH * C3, 256, 0, stream>>>(qkv_pre_b, w_dw, b_dw, qkvb, vb, rq);

  // 3) k norm (q norm fused into dwconv2)
  knorm_kernel<<<(BATCH * CH * SEQ) / 256, 256, 0, stream>>>(qkvb, rk);

  // 4) bf16 prep of qt / kt (coalesced transpose; qt rows permuted+swizzled)
  prep2<<<dim3(32, BATCH * HEADS, 2), 256, 0, stream>>>(
      qkvb, rq, rk, temp, qt, kt);

  // 5) MFMA flash attention -> bf16 attn_t (128-i blocks, 32-i wave strips)
  flash_mfma<<<dim3(SEQ / 128, BATCH * HEADS), 256, 0, stream>>>(
      (const ushort_t*)qt, (const ushort_t*)kt, (const ushort_t*)vb, attn_t);

  // 6) output pointwise conv (bf16 MFMA) -> f32 out
  gemm_mfma_bf16<false><<<dim3(SEQ / 128, DIM / 128, BATCH), 256, 0, stream>>>(
      (const ushort_t*)wpb, (const ushort_t*)attn_t, b_po, out, DIM, SEQ);
}

// Round 11
// 106.135 us; speedup vs baseline: 1.3033x; 1.0504x over previous
//
#include <hip/hip_runtime.h>
#include <hip/hip_bf16.h>

// Problem constants
#define BATCH 4
#define DIM 512
#define HEADS 8
#define CH 64          // DIM/HEADS
#define SEQ 2048
#define C3 1536        // 3*DIM
#define L2EPS 1e-12f

typedef float f32x4 __attribute__((ext_vector_type(4)));
typedef short s16x8 __attribute__((ext_vector_type(8)));
typedef unsigned short ushort_t;

// f32 pair -> packed bf16 pair (RNE) — bit version (memory-bound kernels)
static __device__ __forceinline__ unsigned bfpair(float a, float b) {
  unsigned ua = __builtin_bit_cast(unsigned, a);
  unsigned ub = __builtin_bit_cast(unsigned, b);
  ua = (ua + 0x7FFFu + ((ua >> 16) & 1u)) >> 16;
  ub = (ub + 0x7FFFu + ((ub >> 16) & 1u)) >> 16;
  return ua | (ub << 16);
}

// single f32 -> bf16 (RNE)
static __device__ __forceinline__ ushort_t bf16r(float a) {
  unsigned u = __builtin_bit_cast(unsigned, a);
  u = (u + 0x7FFFu + ((u >> 16) & 1u)) >> 16;
  return (ushort_t)u;
}

// bf16 -> f32
static __device__ __forceinline__ float bf2f(ushort_t u) {
  return __builtin_bit_cast(float, ((unsigned)u) << 16);
}

// f32 pair -> packed bf16 pair via HW cvt (VALU-critical kernels)
static __device__ __forceinline__ unsigned cvtpk(float lo, float hi) {
  unsigned r;
  asm("v_cvt_pk_bf16_f32 %0, %1, %2" : "=v"(r) : "v"(lo), "v"(hi));
  return r;
}

// single-instruction exp2 (skip OCML's denormal-guard expansion; |x|<=~92 here)
static __device__ __forceinline__ float fexp2(float x) {
  float r;
  asm("v_exp_f32 %0, %1" : "=v"(r) : "v"(x));
  return r;
}

// async global->LDS, 16B per lane; lds dest must be wave-uniform base
static __device__ __forceinline__ void gl_lds16(const void* g, void* l) {
  __builtin_amdgcn_global_load_lds(
      (const __attribute__((address_space(1))) unsigned int*)g,
      (__attribute__((address_space(3))) unsigned int*)l, 16, 0, 0);
}

// ---------------------------------------------------------------------------
// Fused input prep (one launch):
//  blocks 0..1023:    x transpose f32 [b][k][n] -> bf16 xbt[b][n][k] swizzled
//  blocks 1024..3071: weight prep f32 [M][512] -> bf16 swizzled
// ---------------------------------------------------------------------------
__global__ __launch_bounds__(256) void prep_inputs(
    const float* __restrict__ x, const float* __restrict__ wq,
    const float* __restrict__ wp, unsigned* __restrict__ xbt,
    unsigned* __restrict__ wqb, unsigned* __restrict__ wpb) {
  __shared__ unsigned T[64][32];
  const int bid = blockIdx.x;
  if (bid < 1024) {
    const int xx = bid & 31, ky = (bid >> 5) & 7, b = bid >> 8;
    const int k0 = ky * 64;
    const int n0 = xx * 64;
    const int nl = threadIdx.x & 63;
    const int dwg = threadIdx.x >> 6;
    const float* xb = x + ((size_t)b * DIM + k0) * SEQ + n0 + nl;
#pragma unroll
    for (int dd = 0; dd < 8; ++dd) {
      const int dw = dwg * 8 + dd;
      const float v0 = xb[(size_t)(2 * dw) * SEQ];
      const float v1 = xb[(size_t)(2 * dw + 1) * SEQ];
      T[nl][dw ^ (4 * (nl & 7))] = bfpair(v0, v1);
    }
    __syncthreads();
#pragma unroll
    for (int rep = 0; rep < 8; ++rep) {
      const int id = rep * 256 + threadIdx.x;
      const int row = id >> 5, dw = id & 31;
      xbt[((size_t)b * SEQ + n0 + row) * 256 + (k0 >> 1) + dw] = T[row][dw];
    }
  } else {
    const int id = (bid - 1024) * 256 + threadIdx.x;
    const float* src;
    unsigned* dst;
    int rid;
    if (id < 1536 * 256) { src = wq; dst = wqb; rid = id; }
    else                 { src = wp; dst = wpb; rid = id - 1536 * 256; }
    const int m = rid >> 8, dcol = rid & 255;
    const int chunk = dcol >> 5, dw = dcol & 31;
    const int sdw = chunk * 32 + (dw ^ (4 * (m & 7)));
    const float* s = src + (size_t)m * 512 + 2 * sdw;
    dst[rid] = bfpair(s[0], s[1]);
  }
}

// ---------------------------------------------------------------------------
// bf16 MFMA GEMM: Y[b][m][n] = sum_k W[m][k] * B[b][n][k] + bias[m], K=512.
// OBF=true: store bf16 (halves HBM write traffic for the qkv_pre intermediate)
// ---------------------------------------------------------------------------
template <bool OBF>
__global__ __launch_bounds__(256) void gemm_mfma_bf16(
    const ushort_t* __restrict__ Wb, const ushort_t* __restrict__ Bt,
    const float* __restrict__ bias, float* __restrict__ Y,
    int M, int N) {
  __shared__ __align__(16) char lds[32768];
  char* As = lds;
  char* Bs = lds + 16384;
  const int b = blockIdx.z;
  const int m0 = blockIdx.y * 128, n0 = blockIdx.x * 128;
  const int t = threadIdx.x, w = t >> 6, lane = t & 63;
  const int l15 = lane & 15, g = lane >> 4;
  const int key = 16 * (l15 & 7);
  const int wm = (w >> 1) * 64, wn = (w & 1) * 64;

  const int rsub = lane >> 3;
  const int csub = (lane & 7) * 8;

  f32x4 acc[4][4] = {};

  const ushort_t* Ag0 = Wb + (size_t)(m0 + 32 * w + rsub) * 512 + csub;
  const ushort_t* Bg0 = Bt + ((size_t)b * N + n0 + 32 * w + rsub) * 512 + csub;
  char* Al0 = As + (32 * w) * 128;
  char* Bl0 = Bs + (32 * w) * 128;

  for (int kc = 0; kc < 8; ++kc) {
    const int ko64 = kc * 64;
#pragma unroll
    for (int ri = 0; ri < 4; ++ri) {
      gl_lds16(Ag0 + (size_t)(8 * ri) * 512 + ko64, Al0 + ri * 1024);
      gl_lds16(Bg0 + (size_t)(8 * ri) * 512 + ko64, Bl0 + ri * 1024);
    }
    __syncthreads();
    const char* Abase = As + (wm + l15) * 128;
    const char* Bbase = Bs + (wn + l15) * 128;
#pragma unroll
    for (int ks = 0; ks < 2; ++ks) {
      const int ko = (64 * ks + 16 * g) ^ key;
      s16x8 af[4], bf[4];
#pragma unroll
      for (int mf = 0; mf < 4; ++mf) af[mf] = *(const s16x8*)(Abase + mf * 2048 + ko);
#pragma unroll
      for (int nf = 0; nf < 4; ++nf) bf[nf] = *(const s16x8*)(Bbase + nf * 2048 + ko);
#pragma unroll
      for (int mf = 0; mf < 4; ++mf)
#pragma unroll
        for (int nf = 0; nf < 4; ++nf)
          acc[mf][nf] = __builtin_amdgcn_mfma_f32_16x16x32_bf16(
              af[mf], bf[nf], acc[mf][nf], 0, 0, 0);
    }
    __syncthreads();
  }

#pragma unroll
  for (int mf = 0; mf < 4; ++mf) {
#pragma unroll
    for (int rg = 0; rg < 4; ++rg) {
      const int m = m0 + wm + 16 * mf + 4 * g + rg;
      const float bv = bias[m];
      if constexpr (OBF) {
        ushort_t* yp =
            (ushort_t*)Y + ((size_t)b * M + m) * N + n0 + wn + l15;
#pragma unroll
        for (int nf = 0; nf < 4; ++nf)
          yp[16 * nf] = bf16r(acc[mf][nf][rg] + bv);
      } else {
        float* yp = Y + ((size_t)b * M + m) * N + n0 + wn + l15;
#pragma unroll
        for (int nf = 0; nf < 4; ++nf)
          yp[16 * nf] = acc[mf][nf][rg] + bv;
      }
    }
  }
}

// ---------------------------------------------------------------------------
// Depthwise conv k=3 pad=1 + bias. One block per (b,channel) row, 8 n/thread.
// bf16 input (qkv_pre); q/k -> bf16 qkv + fused qnorm (f32); v -> bf16 vb
// tile-major [bh][jt64][cc][32 dwords], dword d ^ 4*(cc&7) swizzle.
// ---------------------------------------------------------------------------
__global__ __launch_bounds__(256) void dwconv2(
    const ushort_t* __restrict__ pre, const float* __restrict__ wdw,
    const float* __restrict__ bdw, ushort_t* __restrict__ qkv,
    unsigned* __restrict__ vb, float* __restrict__ rq) {
  __shared__ float red[4];
  const int row = blockIdx.x;           // b*1536 + o
  const int o = row % C3;
  const int b = row / C3;
  const int n0 = threadIdx.x * 8;
  const ushort_t* src = pre + (size_t)row * SEQ + n0;
  const s16x8 mv = *(const s16x8*)src;
  const float left  = (n0 > 0) ? bf2f(src[-1]) : 0.f;
  const float right = (n0 < SEQ - 8) ? bf2f(src[8]) : 0.f;
  const float w0 = wdw[o * 3 + 0], w1 = wdw[o * 3 + 1], w2 = wdw[o * 3 + 2];
  const float bv = bdw[o];
  float mid[8];
#pragma unroll
  for (int u = 0; u < 8; ++u) mid[u] = bf2f((ushort_t)mv[u]);
  const float lf[8] = {left,   mid[0], mid[1], mid[2],
                       mid[3], mid[4], mid[5], mid[6]};
  const float rt[8] = {mid[1], mid[2], mid[3], mid[4],
                       mid[5], mid[6], mid[7], right};
  float y[8];
#pragma unroll
  for (int u = 0; u < 8; ++u) y[u] = w0 * lf[u] + w1 * mid[u] + w2 * rt[u] + bv;

  if (o < 2 * DIM) {
    uint4 pk;
    pk.x = bfpair(y[0], y[1]); pk.y = bfpair(y[2], y[3]);
    pk.z = bfpair(y[4], y[5]); pk.w = bfpair(y[6], y[7]);
    *(uint4*)(qkv + (size_t)row * SEQ + n0) = pk;
    if (o < DIM) {  // uniform branch: whole block is one q row
      float s = 0.f;
#pragma unroll
      for (int u = 0; u < 8; ++u) s += y[u] * y[u];
#pragma unroll
      for (int off = 32; off > 0; off >>= 1) s += __shfl_down(s, off);
      if ((threadIdx.x & 63) == 0) red[threadIdx.x >> 6] = s;
      __syncthreads();
      if (threadIdx.x == 0) {
        const float tv = red[0] + red[1] + red[2] + red[3];
        rq[b * DIM + o] = 1.0f / fmaxf(sqrtf(tv), L2EPS);
      }
    }
  } else {
    const int oc = o - 2 * DIM;
    const int h = oc >> 6, cc = oc & 63;
    const int bh = b * 8 + h;
    const int jt = n0 >> 6, d0 = (n0 & 63) >> 1;
    uint4 pk;
    pk.x = bfpair(y[0], y[1]); pk.y = bfpair(y[2], y[3]);
    pk.z = bfpair(y[4], y[5]); pk.w = bfpair(y[6], y[7]);
    *(uint4*)&vb[((size_t)(bh * 32 + jt) * 64 + cc) * 32 +
                 (d0 ^ (4 * (cc & 7)))] = pk;
  }
}

// ---------------------------------------------------------------------------
// k norm over HEAD axis: rk[b][cc][n]  (bf16 input)
// ---------------------------------------------------------------------------
__global__ __launch_bounds__(256) void knorm_kernel(
    const ushort_t* __restrict__ qkv, float* __restrict__ rk) {
  const int idx = blockIdx.x * 256 + threadIdx.x;
  const int n = idx & (SEQ - 1);
  const int cc = (idx >> 11) & 63;
  const int b = idx >> 17;
  const ushort_t* base = qkv + ((size_t)b * C3 + DIM + cc) * SEQ + n;
  float s = 0.f;
#pragma unroll
  for (int h = 0; h < HEADS; ++h) {
    float v = bf2f(base[(size_t)h * CH * SEQ]);
    s += v * v;
  }
  rk[idx] = 1.0f / fmaxf(sqrtf(s), L2EPS);
}

// ---------------------------------------------------------------------------
// prep2: coalesced LDS-transpose build of qt / kt (bf16 input).
//  sec0 (qt): rows PERMUTED per 32-row slice — actual row jl goes to slice
//    position 16*((jl>>2)&1) + 4*(jl>>3) + (jl&3). This makes the QK^T
//    C-layout (row m=4g+rg at chunk jf) hold actual j = 32*(jf>>1) + 8g +
//    4*(jf&1) + rg, i.e. exp(st) packed with e=4*(jf&1)+rg is a valid K=32
//    PV B-operand with k == natural j. Rows re-swizzled by DEST row
//    (dw ^ 4*(dr&7)) for bank-spread LDS reads in flash.  *rq applied.
//  sec1 (kt): plain layout, * rk * temp * log2(e).
// ---------------------------------------------------------------------------
__global__ __launch_bounds__(256) void prep2(
    const ushort_t* __restrict__ qkv, const float* __restrict__ rq,
    const float* __restrict__ rk, const float* __restrict__ temp,
    unsigned* __restrict__ qt, unsigned* __restrict__ kt) {
  __shared__ unsigned T[64][32];
  const int jt = blockIdx.x, bh = blockIdx.y, sec = blockIdx.z;
  const int b = bh >> 3, h = bh & 7;
  const int jl = threadIdx.x & 63, dwg = threadIdx.x >> 6;
  const int j = jt * 64 + jl;
  if (sec == 0) {
    const ushort_t* base = qkv + ((size_t)b * C3 + h * CH) * SEQ + j;
    const float* rqb = rq + b * DIM + h * CH;
#pragma unroll
    for (int dd = 0; dd < 8; ++dd) {
      const int dw = dwg * 8 + dd;
      float v0 = bf2f(base[(size_t)(2 * dw) * SEQ]) * rqb[2 * dw];
      float v1 = bf2f(base[(size_t)(2 * dw + 1) * SEQ]) * rqb[2 * dw + 1];
      T[jl][dw ^ (4 * (jl & 7))] = bfpair(v0, v1);
    }
  } else {
    const float f = temp[h] * 1.44269504f;
    const ushort_t* base = qkv + ((size_t)b * C3 + DIM + h * CH) * SEQ + j;
    const float* rkb = rk + (size_t)b * CH * SEQ + j;
#pragma unroll
    for (int dd = 0; dd < 8; ++dd) {
      const int dw = dwg * 8 + dd;
      float v0 = bf2f(base[(size_t)(2 * dw) * SEQ]) *
                 rkb[(size_t)(2 * dw) * SEQ] * f;
      float v1 = bf2f(base[(size_t)(2 * dw + 1) * SEQ]) *
                 rkb[(size_t)(2 * dw + 1) * SEQ] * f;
      T[jl][dw ^ (4 * (jl & 7))] = bfpair(v0, v1);
    }
  }
  __syncthreads();
  unsigned* dst = (sec == 0 ? qt : kt) + ((size_t)bh * SEQ + jt * 64) * 32;
#pragma unroll
  for (int rep = 0; rep < 8; ++rep) {
    const int id = rep * 256 + threadIdx.x;
    const int row = id >> 5, dw = id & 31;
    const unsigned val = T[row][dw ^ (4 * (row & 7))];
    if (sec == 0) {
      const int s = row >> 5, rl = row & 31;
      const int dr = (s << 5) | (16 * ((rl >> 2) & 1) + 4 * (rl >> 3) + (rl & 3));
      dst[dr * 32 + (dw ^ (4 * (dr & 7)))] = val;
    } else {
      dst[row * 32 + dw] = val;
    }
  }
}

// ---------------------------------------------------------------------------
// Flash attention v11 = v8 (passing) + paired j-tiles per barrier period +
// V-fragment hoist. Rationale (R7/R10 counters): 1700 cyc/wave-tile vs ~400
// issue => latency/barrier-bound. Pairing tiles halves barrier count (32->16)
// and doubles the DMA drain cover (~600cyc); hoisting the 8 V ds_reads to
// compute() entry hides their ~120cyc latency under QK^T+exp. compute() math,
// qt permutation, and epilogue are byte-identical to v8. LDS 64KB, 2 blk/CU
// (unchanged effective occupancy: grid 512).
// ---------------------------------------------------------------------------
__global__ __launch_bounds__(256, 2) void flash_mfma(
    const ushort_t* __restrict__ qt, const ushort_t* __restrict__ kt,
    const ushort_t* __restrict__ vb, unsigned* __restrict__ attn_t) {
  __shared__ __align__(16) char lds[65536];
  char* const QA = lds;             // tiles 4s, 4s+1   [2 x 64 pos x 128B]
  char* const QB = lds + 16384;     // tiles 4s+2, 4s+3
  char* const VA = lds + 32768;
  char* const VB = lds + 49152;

  // XCD-aware bijective swizzle over 512 blocks: 64 per XCD = 4 bh values
  const int orig = blockIdx.y * 16 + blockIdx.x;
  const int swz = (orig & 7) * 64 + (orig >> 3);
  const int bh = swz >> 4, b = bh >> 3, h = bh & 7;
  const int i0 = (swz & 15) * 128;

  const int t = threadIdx.x, w = t >> 6, lane = t & 63;
  const int l15 = lane & 15, g = lane >> 4;
  const int key = 16 * (lane & 7);

  // K fragments for the wave's two 16-i blocks: 32 VGPR
  const ushort_t* ktp =
      kt + ((size_t)bh * SEQ + i0 + 32 * w + l15) * 64 + 8 * g;
  s16x8 kf0[2], kf1[2];
#pragma unroll
  for (int ib = 0; ib < 2; ++ib) {
    kf0[ib] = *(const s16x8*)(ktp + ib * 1024);
    kf1[ib] = *(const s16x8*)(ktp + ib * 1024 + 32);
  }

  const ushort_t* qtile = qt + (size_t)bh * SEQ * 64;    // + jt*4096
  const ushort_t* vtile = vb + (size_t)bh * 32 * 4096;   // + jt*4096

  // wave-level staging: 2 chunks of 1KB each per tile for Q and V
  const int li0 = (w * 2) * 64 + lane;
  const int li1 = li0 + 64;
  const int wo = (w * 2) * 1024;

  f32x4 accO[4][2] = {};   // [mf(cc)][ib]
  float lr[2] = {};

// stage tiles JT and JT+1 into (QD,VD): [0,8K) = JT, [8K,16K) = JT+1
#define FSTAGE2(JT, QD, VD)                                               \
  do {                                                                    \
    gl_lds16(qtile + (size_t)(JT) * 4096 + li0 * 8, (QD) + wo);           \
    gl_lds16(qtile + (size_t)(JT) * 4096 + li1 * 8, (QD) + wo + 1024);    \
    gl_lds16(qtile + (size_t)(JT + 1) * 4096 + li0 * 8, (QD) + 8192 + wo);\
    gl_lds16(qtile + (size_t)(JT + 1) * 4096 + li1 * 8,                   \
             (QD) + 8192 + wo + 1024);                                    \
    gl_lds16(vtile + (size_t)(JT) * 4096 + li0 * 8, (VD) + wo);           \
    gl_lds16(vtile + (size_t)(JT) * 4096 + li1 * 8, (VD) + wo + 1024);    \
    gl_lds16(vtile + (size_t)(JT + 1) * 4096 + li0 * 8, (VD) + 8192 + wo);\
    gl_lds16(vtile + (size_t)(JT + 1) * 4096 + li1 * 8,                   \
             (VD) + 8192 + wo + 1024);                                    \
  } while (0)

  auto compute = [&](const char* Qs, const char* Vs) {
    // hoist V fragment reads: independent of QK^T, consumed after exp —
    // their LDS latency hides under the QK^T MFMAs + exp chain.
    s16x8 vf[2][4];
#pragma unroll
    for (int ks = 0; ks < 2; ++ks)
#pragma unroll
      for (int mf = 0; mf < 4; ++mf)
        vf[ks][mf] = *(const s16x8*)(Vs + (16 * mf + l15) * 128 +
                                     ((16 * g + 64 * ks) ^ key));

    f32x4 st[4][2];
    __builtin_amdgcn_s_setprio(1);
#pragma unroll
    for (int jf = 0; jf < 4; ++jf) {
      const char* qrow = Qs + (16 * jf + l15) * 128;
      s16x8 a0 = *(const s16x8*)(qrow + ((16 * g) ^ key));
      s16x8 a1 = *(const s16x8*)(qrow + ((16 * g + 64) ^ key));
#pragma unroll
      for (int ib = 0; ib < 2; ++ib) {
        f32x4 z = {};
        z = __builtin_amdgcn_mfma_f32_16x16x32_bf16(a0, kf0[ib], z, 0, 0, 0);
        z = __builtin_amdgcn_mfma_f32_16x16x32_bf16(a1, kf1[ib], z, 0, 0, 0);
        st[jf][ib] = z;
      }
    }
    __builtin_amdgcn_s_setprio(0);

    // P = exp2(st) in regs; permuted qt makes pb a valid K=32 B-operand
    s16x8 pb[2][2];
#pragma unroll
    for (int ib = 0; ib < 2; ++ib)
#pragma unroll
      for (int ks = 0; ks < 2; ++ks) {
        const float e0 = fexp2(st[2 * ks][ib][0]);
        const float e1 = fexp2(st[2 * ks][ib][1]);
        const float e2 = fexp2(st[2 * ks][ib][2]);
        const float e3 = fexp2(st[2 * ks][ib][3]);
        const float e4 = fexp2(st[2 * ks + 1][ib][0]);
        const float e5 = fexp2(st[2 * ks + 1][ib][1]);
        const float e6 = fexp2(st[2 * ks + 1][ib][2]);
        const float e7 = fexp2(st[2 * ks + 1][ib][3]);
        lr[ib] += ((e0 + e1) + (e2 + e3)) + ((e4 + e5) + (e6 + e7));
        uint4 u;
        u.x = cvtpk(e0, e1);
        u.y = cvtpk(e2, e3);
        u.z = cvtpk(e4, e5);
        u.w = cvtpk(e6, e7);
        pb[ib][ks] = __builtin_bit_cast(s16x8, u);
      }

    __builtin_amdgcn_s_setprio(1);
#pragma unroll
    for (int ks = 0; ks < 2; ++ks)
#pragma unroll
      for (int mf = 0; mf < 4; ++mf)
#pragma unroll
        for (int ib = 0; ib < 2; ++ib)
          accO[mf][ib] = __builtin_amdgcn_mfma_f32_16x16x32_bf16(
              vf[ks][mf], pb[ib][ks], accO[mf][ib], 0, 0, 0);
    __builtin_amdgcn_s_setprio(0);
  };

  FSTAGE2(0, QA, VA);
  __syncthreads();
#pragma unroll 1
  for (int s = 0; s < 8; ++s) {
    const int t4 = 4 * s;
    FSTAGE2(t4 + 2, QB, VB);           // in flight across 2 computes
    compute(QA, VA);                   // tile t4
    compute(QA + 8192, VA + 8192);     // tile t4+1
    __syncthreads();                   // drain: QB/VB ready
    if (s < 7) FSTAGE2(t4 + 4, QA, VA);
    compute(QB, VB);                   // tile t4+2
    compute(QB + 8192, VB + 8192);     // tile t4+3
    __syncthreads();
  }

  // ---- deferred l reduction over the 4 j-row-groups ----
  float inv[2];
#pragma unroll
  for (int ib = 0; ib < 2; ++ib) {
    lr[ib] += __shfl_xor(lr[ib], 16);
    lr[ib] += __shfl_xor(lr[ib], 32);
    inv[ib] = 1.0f / lr[ib];
  }

  // ---- epilogue: bf16 attn_t, swizzled k-major [b][i][c] ----
  unsigned* Pw = (unsigned*)(lds + w * 4096);  // 32 rows x 128B per wave
  const int kk = 4 * (l15 & 7);
#pragma unroll
  for (int ib = 0; ib < 2; ++ib)
#pragma unroll
    for (int mf = 0; mf < 4; ++mf) {
      uint2 pk;
      pk.x = cvtpk(accO[mf][ib][0] * inv[ib], accO[mf][ib][1] * inv[ib]);
      pk.y = cvtpk(accO[mf][ib][2] * inv[ib], accO[mf][ib][3] * inv[ib]);
      const int dwb = 8 * mf + 2 * g;
      *(uint2*)&Pw[(16 * ib + l15) * 32 + (dwb ^ kk)] = pk;
    }
  __syncthreads();
#pragma unroll
  for (int rep = 0; rep < 16; ++rep) {
    const int id = rep * 64 + lane;
    const int row = id >> 5, dw = id & 31;
    attn_t[((size_t)b * SEQ + i0 + 32 * w + row) * 256 + h * 32 + dw] =
        Pw[row * 32 + dw];
  }
#undef FSTAGE2
}

// ---------------------------------------------------------------------------
extern "C" void kernel_launch(void* const* d_in, const int* in_sizes, int n_in,
                              void* d_out, int out_size, void* d_ws, size_t ws_size,
                              hipStream_t stream) {
  const float* x      = (const float*)d_in[0];
  const float* w_qkv  = (const float*)d_in[1];
  const float* b_qkv  = (const float*)d_in[2];
  const float* w_dw   = (const float*)d_in[3];
  const float* b_dw   = (const float*)d_in[4];
  const float* w_po   = (const float*)d_in[5];
  const float* b_po   = (const float*)d_in[6];
  const float* temp   = (const float*)d_in[7];
  float* out = (float*)d_out;
  float* ws  = (float*)d_ws;

  // workspace layout (float units; qkv_pre/qkv bf16 inside their regions)
  ushort_t* qkv_pre_b = (ushort_t*)ws;            // 12.58M bf16 (fits region)
  ushort_t* qkvb = (ushort_t*)(ws + 12582912);    // 12.58M bf16 (q,k used)
  float* rq      = ws + 25165824;                 // 2048
  float* rk      = ws + 25167872;                 // 524,288
  unsigned* xbt  = (unsigned*)(ws + 25692160);    // 2M dwords (8MB)
  unsigned* wqb  = (unsigned*)(ws + 27789312);    // 384K dwords
  unsigned* wpb  = (unsigned*)(ws + 28182528);    // 128K dwords
  // xbt region reused after QKV GEMM:
  unsigned* vb     = (unsigned*)(ws + 25692160);  // 2M dwords (dwconv2 output)
  // qkv_pre region reused after dwconv2:
  unsigned* qt     = (unsigned*)(ws);             // 2M dwords
  unsigned* kt     = (unsigned*)(ws + 2097152);   // 2M dwords
  unsigned* attn_t = (unsigned*)(ws + 4194304);   // 2M dwords

  // 0) fused bf16 conversions (x transpose + weight prep, one launch)
  prep_inputs<<<3072, 256, 0, stream>>>(x, w_qkv, w_po, xbt, wqb, wpb);

  // 1) QKV pointwise conv (bf16 MFMA) -> bf16 qkv_pre
  gemm_mfma_bf16<true><<<dim3(SEQ / 128, C3 / 128, BATCH), 256, 0, stream>>>(
      (const ushort_t*)wqb, (const ushort_t*)xbt, b_qkv,
      (float*)qkv_pre_b, C3, SEQ);

  // 2) depthwise conv (bf16 in); v -> bf16 vb, q/k -> bf16 qkv; qnorm fused
  dwconv2<<<BATCH * C3, 256, 0, stream>>>(qkv_pre_b, w_dw, b_dw, qkvb, vb, rq);

  // 3) k norm (q norm fused into dwconv2)
  knorm_kernel<<<(BATCH * CH * SEQ) / 256, 256, 0, stream>>>(qkvb, rk);

  // 4) bf16 prep of qt / kt (coalesced transpose; qt rows permuted+swizzled)
  prep2<<<dim3(32, BATCH * HEADS, 2), 256, 0, stream>>>(
      qkvb, rq, rk, temp, qt, kt);

  // 5) MFMA flash attention -> bf16 attn_t (128-i blocks, paired j-tiles)
  flash_mfma<<<dim3(SEQ / 128, BATCH * HEADS), 256, 0, stream>>>(
      (const ushort_t*)qt, (const ushort_t*)kt, (const ushort_t*)vb, attn_t);

  // 6) output pointwise conv (bf16 MFMA) -> f32 out
  gemm_mfma_bf16<false><<<dim3(SEQ / 128, DIM / 128, BATCH), 256, 0, stream>>>(
      (const ushort_t*)wpb, (const ushort_t*)attn_t, b_po, out, DIM, SEQ);
}

// Round 12
// 102.222 us; speedup vs baseline: 1.3532x; 1.0383x over previous
//
#include <hip/hip_runtime.h>
#include <hip/hip_bf16.h>

// Problem constants
#define BATCH 4
#define DIM 512
#define HEADS 8
#define CH 64          // DIM/HEADS
#define SEQ 2048
#define C3 1536        // 3*DIM
#define L2EPS 1e-12f

typedef float f32x4 __attribute__((ext_vector_type(4)));
typedef short s16x8 __attribute__((ext_vector_type(8)));
typedef unsigned short ushort_t;

// f32 pair -> packed bf16 pair (RNE) — bit version (memory-bound kernels)
static __device__ __forceinline__ unsigned bfpair(float a, float b) {
  unsigned ua = __builtin_bit_cast(unsigned, a);
  unsigned ub = __builtin_bit_cast(unsigned, b);
  ua = (ua + 0x7FFFu + ((ua >> 16) & 1u)) >> 16;
  ub = (ub + 0x7FFFu + ((ub >> 16) & 1u)) >> 16;
  return ua | (ub << 16);
}

// single f32 -> bf16 (RNE)
static __device__ __forceinline__ ushort_t bf16r(float a) {
  unsigned u = __builtin_bit_cast(unsigned, a);
  u = (u + 0x7FFFu + ((u >> 16) & 1u)) >> 16;
  return (ushort_t)u;
}

// bf16 -> f32
static __device__ __forceinline__ float bf2f(ushort_t u) {
  return __builtin_bit_cast(float, ((unsigned)u) << 16);
}

// f32 pair -> packed bf16 pair via HW cvt (VALU-critical kernels)
static __device__ __forceinline__ unsigned cvtpk(float lo, float hi) {
  unsigned r;
  asm("v_cvt_pk_bf16_f32 %0, %1, %2" : "=v"(r) : "v"(lo), "v"(hi));
  return r;
}

// single-instruction exp2 (skip OCML's denormal-guard expansion; |x|<=~92 here)
static __device__ __forceinline__ float fexp2(float x) {
  float r;
  asm("v_exp_f32 %0, %1" : "=v"(r) : "v"(x));
  return r;
}

// async global->LDS, 16B per lane; lds dest must be wave-uniform base
static __device__ __forceinline__ void gl_lds16(const void* g, void* l) {
  __builtin_amdgcn_global_load_lds(
      (const __attribute__((address_space(1))) unsigned int*)g,
      (__attribute__((address_space(3))) unsigned int*)l, 16, 0, 0);
}

// ---------------------------------------------------------------------------
// Fused input prep (one launch):
//  blocks 0..1023:    x transpose f32 [b][k][n] -> bf16 xbt[b][n][k] swizzled
//  blocks 1024..3071: weight prep f32 [M][512] -> bf16 swizzled
// ---------------------------------------------------------------------------
__global__ __launch_bounds__(256) void prep_inputs(
    const float* __restrict__ x, const float* __restrict__ wq,
    const float* __restrict__ wp, unsigned* __restrict__ xbt,
    unsigned* __restrict__ wqb, unsigned* __restrict__ wpb) {
  __shared__ unsigned T[64][32];
  const int bid = blockIdx.x;
  if (bid < 1024) {
    const int xx = bid & 31, ky = (bid >> 5) & 7, b = bid >> 8;
    const int k0 = ky * 64;
    const int n0 = xx * 64;
    const int nl = threadIdx.x & 63;
    const int dwg = threadIdx.x >> 6;
    const float* xb = x + ((size_t)b * DIM + k0) * SEQ + n0 + nl;
#pragma unroll
    for (int dd = 0; dd < 8; ++dd) {
      const int dw = dwg * 8 + dd;
      const float v0 = xb[(size_t)(2 * dw) * SEQ];
      const float v1 = xb[(size_t)(2 * dw + 1) * SEQ];
      T[nl][dw ^ (4 * (nl & 7))] = bfpair(v0, v1);
    }
    __syncthreads();
#pragma unroll
    for (int rep = 0; rep < 8; ++rep) {
      const int id = rep * 256 + threadIdx.x;
      const int row = id >> 5, dw = id & 31;
      xbt[((size_t)b * SEQ + n0 + row) * 256 + (k0 >> 1) + dw] = T[row][dw];
    }
  } else {
    const int id = (bid - 1024) * 256 + threadIdx.x;
    const float* src;
    unsigned* dst;
    int rid;
    if (id < 1536 * 256) { src = wq; dst = wqb; rid = id; }
    else                 { src = wp; dst = wpb; rid = id - 1536 * 256; }
    const int m = rid >> 8, dcol = rid & 255;
    const int chunk = dcol >> 5, dw = dcol & 31;
    const int sdw = chunk * 32 + (dw ^ (4 * (m & 7)));
    const float* s = src + (size_t)m * 512 + 2 * sdw;
    dst[rid] = bfpair(s[0], s[1]);
  }
}

// ---------------------------------------------------------------------------
// bf16 MFMA GEMM: Y[b][m][n] = sum_k W[m][k] * B[b][n][k] + bias[m], K=512.
// OBF=true: store bf16. BM = M-tile (128 or 64); BM=64 doubles block count
// for occupancy when M is small (gemm2: M=512 -> 512 blocks = 2/CU vs 1/CU).
// ---------------------------------------------------------------------------
template <bool OBF, int BM>
__global__ __launch_bounds__(256) void gemm_mfma_bf16(
    const ushort_t* __restrict__ Wb, const ushort_t* __restrict__ Bt,
    const float* __restrict__ bias, float* __restrict__ Y,
    int M, int N) {
  constexpr int AW = BM / 4;    // A rows staged per wave
  constexpr int MFR = BM / 32;  // m-fragments per wave
  __shared__ __align__(16) char lds[BM * 128 + 16384];
  char* As = lds;
  char* Bs = lds + BM * 128;
  const int b = blockIdx.z;
  const int m0 = blockIdx.y * BM, n0 = blockIdx.x * 128;
  const int t = threadIdx.x, w = t >> 6, lane = t & 63;
  const int l15 = lane & 15, g = lane >> 4;
  const int key = 16 * (l15 & 7);
  const int wm = (w >> 1) * (BM / 2), wn = (w & 1) * 64;

  const int rsub = lane >> 3;
  const int csub = (lane & 7) * 8;

  f32x4 acc[MFR][4] = {};

  const ushort_t* Ag0 = Wb + (size_t)(m0 + AW * w + rsub) * 512 + csub;
  const ushort_t* Bg0 = Bt + ((size_t)b * N + n0 + 32 * w + rsub) * 512 + csub;
  char* Al0 = As + (AW * w) * 128;
  char* Bl0 = Bs + (32 * w) * 128;

  for (int kc = 0; kc < 8; ++kc) {
    const int ko64 = kc * 64;
#pragma unroll
    for (int ri = 0; ri < 4; ++ri) {
      if (ri < AW / 8)
        gl_lds16(Ag0 + (size_t)(8 * ri) * 512 + ko64, Al0 + ri * 1024);
      gl_lds16(Bg0 + (size_t)(8 * ri) * 512 + ko64, Bl0 + ri * 1024);
    }
    __syncthreads();
    const char* Abase = As + (wm + l15) * 128;
    const char* Bbase = Bs + (wn + l15) * 128;
#pragma unroll
    for (int ks = 0; ks < 2; ++ks) {
      const int ko = (64 * ks + 16 * g) ^ key;
      s16x8 af[MFR], bf[4];
#pragma unroll
      for (int mf = 0; mf < MFR; ++mf) af[mf] = *(const s16x8*)(Abase + mf * 2048 + ko);
#pragma unroll
      for (int nf = 0; nf < 4; ++nf) bf[nf] = *(const s16x8*)(Bbase + nf * 2048 + ko);
#pragma unroll
      for (int mf = 0; mf < MFR; ++mf)
#pragma unroll
        for (int nf = 0; nf < 4; ++nf)
          acc[mf][nf] = __builtin_amdgcn_mfma_f32_16x16x32_bf16(
              af[mf], bf[nf], acc[mf][nf], 0, 0, 0);
    }
    __syncthreads();
  }

#pragma unroll
  for (int mf = 0; mf < MFR; ++mf) {
#pragma unroll
    for (int rg = 0; rg < 4; ++rg) {
      const int m = m0 + wm + 16 * mf + 4 * g + rg;
      const float bv = bias[m];
      if constexpr (OBF) {
        ushort_t* yp =
            (ushort_t*)Y + ((size_t)b * M + m) * N + n0 + wn + l15;
#pragma unroll
        for (int nf = 0; nf < 4; ++nf)
          yp[16 * nf] = bf16r(acc[mf][nf][rg] + bv);
      } else {
        float* yp = Y + ((size_t)b * M + m) * N + n0 + wn + l15;
#pragma unroll
        for (int nf = 0; nf < 4; ++nf)
          yp[16 * nf] = acc[mf][nf][rg] + bv;
      }
    }
  }
}

// ---------------------------------------------------------------------------
// Depthwise conv k=3 pad=1 + bias. One block per (b,channel) row, 8 n/thread.
// bf16 input (qkv_pre); q/k -> bf16 qkv + fused qnorm (f32); v -> bf16 vb
// tile-major [bh][jt64][cc][32 dwords], dword d ^ 4*(cc&7) swizzle.
// ---------------------------------------------------------------------------
__global__ __launch_bounds__(256) void dwconv2(
    const ushort_t* __restrict__ pre, const float* __restrict__ wdw,
    const float* __restrict__ bdw, ushort_t* __restrict__ qkv,
    unsigned* __restrict__ vb, float* __restrict__ rq) {
  __shared__ float red[4];
  const int row = blockIdx.x;           // b*1536 + o
  const int o = row % C3;
  const int b = row / C3;
  const int n0 = threadIdx.x * 8;
  const ushort_t* src = pre + (size_t)row * SEQ + n0;
  const s16x8 mv = *(const s16x8*)src;
  const float left  = (n0 > 0) ? bf2f(src[-1]) : 0.f;
  const float right = (n0 < SEQ - 8) ? bf2f(src[8]) : 0.f;
  const float w0 = wdw[o * 3 + 0], w1 = wdw[o * 3 + 1], w2 = wdw[o * 3 + 2];
  const float bv = bdw[o];
  float mid[8];
#pragma unroll
  for (int u = 0; u < 8; ++u) mid[u] = bf2f((ushort_t)mv[u]);
  const float lf[8] = {left,   mid[0], mid[1], mid[2],
                       mid[3], mid[4], mid[5], mid[6]};
  const float rt[8] = {mid[1], mid[2], mid[3], mid[4],
                       mid[5], mid[6], mid[7], right};
  float y[8];
#pragma unroll
  for (int u = 0; u < 8; ++u) y[u] = w0 * lf[u] + w1 * mid[u] + w2 * rt[u] + bv;

  if (o < 2 * DIM) {
    uint4 pk;
    pk.x = bfpair(y[0], y[1]); pk.y = bfpair(y[2], y[3]);
    pk.z = bfpair(y[4], y[5]); pk.w = bfpair(y[6], y[7]);
    *(uint4*)(qkv + (size_t)row * SEQ + n0) = pk;
    if (o < DIM) {  // uniform branch: whole block is one q row
      float s = 0.f;
#pragma unroll
      for (int u = 0; u < 8; ++u) s += y[u] * y[u];
#pragma unroll
      for (int off = 32; off > 0; off >>= 1) s += __shfl_down(s, off);
      if ((threadIdx.x & 63) == 0) red[threadIdx.x >> 6] = s;
      __syncthreads();
      if (threadIdx.x == 0) {
        const float tv = red[0] + red[1] + red[2] + red[3];
        rq[b * DIM + o] = 1.0f / fmaxf(sqrtf(tv), L2EPS);
      }
    }
  } else {
    const int oc = o - 2 * DIM;
    const int h = oc >> 6, cc = oc & 63;
    const int bh = b * 8 + h;
    const int jt = n0 >> 6, d0 = (n0 & 63) >> 1;
    uint4 pk;
    pk.x = bfpair(y[0], y[1]); pk.y = bfpair(y[2], y[3]);
    pk.z = bfpair(y[4], y[5]); pk.w = bfpair(y[6], y[7]);
    *(uint4*)&vb[((size_t)(bh * 32 + jt) * 64 + cc) * 32 +
                 (d0 ^ (4 * (cc & 7)))] = pk;
  }
}

// ---------------------------------------------------------------------------
// k norm over HEAD axis: rk[b][cc][n]  (bf16 input)
// ---------------------------------------------------------------------------
__global__ __launch_bounds__(256) void knorm_kernel(
    const ushort_t* __restrict__ qkv, float* __restrict__ rk) {
  const int idx = blockIdx.x * 256 + threadIdx.x;
  const int n = idx & (SEQ - 1);
  const int cc = (idx >> 11) & 63;
  const int b = idx >> 17;
  const ushort_t* base = qkv + ((size_t)b * C3 + DIM + cc) * SEQ + n;
  float s = 0.f;
#pragma unroll
  for (int h = 0; h < HEADS; ++h) {
    float v = bf2f(base[(size_t)h * CH * SEQ]);
    s += v * v;
  }
  rk[idx] = 1.0f / fmaxf(sqrtf(s), L2EPS);
}

// ---------------------------------------------------------------------------
// prep2: coalesced LDS-transpose build of qt / kt (bf16 input).
//  sec0 (qt): rows PERMUTED per 32-row slice — actual row jl goes to slice
//    position 16*((jl>>2)&1) + 4*(jl>>3) + (jl&3). This makes the QK^T
//    C-layout (row m=4g+rg at chunk jf) hold actual j = 32*(jf>>1) + 8g +
//    4*(jf&1) + rg, i.e. exp(st) packed with e=4*(jf&1)+rg is a valid K=32
//    PV B-operand with k == natural j. Rows re-swizzled by DEST row
//    (dw ^ 4*(dr&7)) for bank-spread LDS reads in flash.  *rq applied.
//  sec1 (kt): plain layout, * rk * temp * log2(e).
// ---------------------------------------------------------------------------
__global__ __launch_bounds__(256) void prep2(
    const ushort_t* __restrict__ qkv, const float* __restrict__ rq,
    const float* __restrict__ rk, const float* __restrict__ temp,
    unsigned* __restrict__ qt, unsigned* __restrict__ kt) {
  __shared__ unsigned T[64][32];
  const int jt = blockIdx.x, bh = blockIdx.y, sec = blockIdx.z;
  const int b = bh >> 3, h = bh & 7;
  const int jl = threadIdx.x & 63, dwg = threadIdx.x >> 6;
  const int j = jt * 64 + jl;
  if (sec == 0) {
    const ushort_t* base = qkv + ((size_t)b * C3 + h * CH) * SEQ + j;
    const float* rqb = rq + b * DIM + h * CH;
#pragma unroll
    for (int dd = 0; dd < 8; ++dd) {
      const int dw = dwg * 8 + dd;
      float v0 = bf2f(base[(size_t)(2 * dw) * SEQ]) * rqb[2 * dw];
      float v1 = bf2f(base[(size_t)(2 * dw + 1) * SEQ]) * rqb[2 * dw + 1];
      T[jl][dw ^ (4 * (jl & 7))] = bfpair(v0, v1);
    }
  } else {
    const float f = temp[h] * 1.44269504f;
    const ushort_t* base = qkv + ((size_t)b * C3 + DIM + h * CH) * SEQ + j;
    const float* rkb = rk + (size_t)b * CH * SEQ + j;
#pragma unroll
    for (int dd = 0; dd < 8; ++dd) {
      const int dw = dwg * 8 + dd;
      float v0 = bf2f(base[(size_t)(2 * dw) * SEQ]) *
                 rkb[(size_t)(2 * dw) * SEQ] * f;
      float v1 = bf2f(base[(size_t)(2 * dw + 1) * SEQ]) *
                 rkb[(size_t)(2 * dw + 1) * SEQ] * f;
      T[jl][dw ^ (4 * (jl & 7))] = bfpair(v0, v1);
    }
  }
  __syncthreads();
  unsigned* dst = (sec == 0 ? qt : kt) + ((size_t)bh * SEQ + jt * 64) * 32;
#pragma unroll
  for (int rep = 0; rep < 8; ++rep) {
    const int id = rep * 256 + threadIdx.x;
    const int row = id >> 5, dw = id & 31;
    const unsigned val = T[row][dw ^ (4 * (row & 7))];
    if (sec == 0) {
      const int s = row >> 5, rl = row & 31;
      const int dr = (s << 5) | (16 * ((rl >> 2) & 1) + 4 * (rl >> 3) + (rl & 3));
      dst[dr * 32 + (dw ^ (4 * (dr & 7)))] = val;
    } else {
      dst[row * 32 + dw] = val;
    }
  }
}

// ---------------------------------------------------------------------------
// Flash attention v11: 32-i wave strips, 128-i blocks, paired j-tiles per
// barrier period + V-fragment hoist. P in registers via qt row permutation.
// ---------------------------------------------------------------------------
__global__ __launch_bounds__(256, 2) void flash_mfma(
    const ushort_t* __restrict__ qt, const ushort_t* __restrict__ kt,
    const ushort_t* __restrict__ vb, unsigned* __restrict__ attn_t) {
  __shared__ __align__(16) char lds[65536];
  char* const QA = lds;             // tiles 4s, 4s+1   [2 x 64 pos x 128B]
  char* const QB = lds + 16384;     // tiles 4s+2, 4s+3
  char* const VA = lds + 32768;
  char* const VB = lds + 49152;

  // XCD-aware bijective swizzle over 512 blocks: 64 per XCD = 4 bh values
  const int orig = blockIdx.y * 16 + blockIdx.x;
  const int swz = (orig & 7) * 64 + (orig >> 3);
  const int bh = swz >> 4, b = bh >> 3, h = bh & 7;
  const int i0 = (swz & 15) * 128;

  const int t = threadIdx.x, w = t >> 6, lane = t & 63;
  const int l15 = lane & 15, g = lane >> 4;
  const int key = 16 * (lane & 7);

  // K fragments for the wave's two 16-i blocks: 32 VGPR
  const ushort_t* ktp =
      kt + ((size_t)bh * SEQ + i0 + 32 * w + l15) * 64 + 8 * g;
  s16x8 kf0[2], kf1[2];
#pragma unroll
  for (int ib = 0; ib < 2; ++ib) {
    kf0[ib] = *(const s16x8*)(ktp + ib * 1024);
    kf1[ib] = *(const s16x8*)(ktp + ib * 1024 + 32);
  }

  const ushort_t* qtile = qt + (size_t)bh * SEQ * 64;    // + jt*4096
  const ushort_t* vtile = vb + (size_t)bh * 32 * 4096;   // + jt*4096

  // wave-level staging: 2 chunks of 1KB each per tile for Q and V
  const int li0 = (w * 2) * 64 + lane;
  const int li1 = li0 + 64;
  const int wo = (w * 2) * 1024;

  f32x4 accO[4][2] = {};   // [mf(cc)][ib]
  float lr[2] = {};

// stage tiles JT and JT+1 into (QD,VD): [0,8K) = JT, [8K,16K) = JT+1
#define FSTAGE2(JT, QD, VD)                                               \
  do {                                                                    \
    gl_lds16(qtile + (size_t)(JT) * 4096 + li0 * 8, (QD) + wo);           \
    gl_lds16(qtile + (size_t)(JT) * 4096 + li1 * 8, (QD) + wo + 1024);    \
    gl_lds16(qtile + (size_t)(JT + 1) * 4096 + li0 * 8, (QD) + 8192 + wo);\
    gl_lds16(qtile + (size_t)(JT + 1) * 4096 + li1 * 8,                   \
             (QD) + 8192 + wo + 1024);                                    \
    gl_lds16(vtile + (size_t)(JT) * 4096 + li0 * 8, (VD) + wo);           \
    gl_lds16(vtile + (size_t)(JT) * 4096 + li1 * 8, (VD) + wo + 1024);    \
    gl_lds16(vtile + (size_t)(JT + 1) * 4096 + li0 * 8, (VD) + 8192 + wo);\
    gl_lds16(vtile + (size_t)(JT + 1) * 4096 + li1 * 8,                   \
             (VD) + 8192 + wo + 1024);                                    \
  } while (0)

  auto compute = [&](const char* Qs, const char* Vs) {
    // hoist V fragment reads: independent of QK^T, consumed after exp —
    // their LDS latency hides under the QK^T MFMAs + exp chain.
    s16x8 vf[2][4];
#pragma unroll
    for (int ks = 0; ks < 2; ++ks)
#pragma unroll
      for (int mf = 0; mf < 4; ++mf)
        vf[ks][mf] = *(const s16x8*)(Vs + (16 * mf + l15) * 128 +
                                     ((16 * g + 64 * ks) ^ key));

    f32x4 st[4][2];
    __builtin_amdgcn_s_setprio(1);
#pragma unroll
    for (int jf = 0; jf < 4; ++jf) {
      const char* qrow = Qs + (16 * jf + l15) * 128;
      s16x8 a0 = *(const s16x8*)(qrow + ((16 * g) ^ key));
      s16x8 a1 = *(const s16x8*)(qrow + ((16 * g + 64) ^ key));
#pragma unroll
      for (int ib = 0; ib < 2; ++ib) {
        f32x4 z = {};
        z = __builtin_amdgcn_mfma_f32_16x16x32_bf16(a0, kf0[ib], z, 0, 0, 0);
        z = __builtin_amdgcn_mfma_f32_16x16x32_bf16(a1, kf1[ib], z, 0, 0, 0);
        st[jf][ib] = z;
      }
    }
    __builtin_amdgcn_s_setprio(0);

    // P = exp2(st) in regs; permuted qt makes pb a valid K=32 B-operand
    s16x8 pb[2][2];
#pragma unroll
    for (int ib = 0; ib < 2; ++ib)
#pragma unroll
      for (int ks = 0; ks < 2; ++ks) {
        const float e0 = fexp2(st[2 * ks][ib][0]);
        const float e1 = fexp2(st[2 * ks][ib][1]);
        const float e2 = fexp2(st[2 * ks][ib][2]);
        const float e3 = fexp2(st[2 * ks][ib][3]);
        const float e4 = fexp2(st[2 * ks + 1][ib][0]);
        const float e5 = fexp2(st[2 * ks + 1][ib][1]);
        const float e6 = fexp2(st[2 * ks + 1][ib][2]);
        const float e7 = fexp2(st[2 * ks + 1][ib][3]);
        lr[ib] += ((e0 + e1) + (e2 + e3)) + ((e4 + e5) + (e6 + e7));
        uint4 u;
        u.x = cvtpk(e0, e1);
        u.y = cvtpk(e2, e3);
        u.z = cvtpk(e4, e5);
        u.w = cvtpk(e6, e7);
        pb[ib][ks] = __builtin_bit_cast(s16x8, u);
      }

    __builtin_amdgcn_s_setprio(1);
#pragma unroll
    for (int ks = 0; ks < 2; ++ks)
#pragma unroll
      for (int mf = 0; mf < 4; ++mf)
#pragma unroll
        for (int ib = 0; ib < 2; ++ib)
          accO[mf][ib] = __builtin_amdgcn_mfma_f32_16x16x32_bf16(
              vf[ks][mf], pb[ib][ks], accO[mf][ib], 0, 0, 0);
    __builtin_amdgcn_s_setprio(0);
  };

  FSTAGE2(0, QA, VA);
  __syncthreads();
#pragma unroll 1
  for (int s = 0; s < 8; ++s) {
    const int t4 = 4 * s;
    FSTAGE2(t4 + 2, QB, VB);           // in flight across 2 computes
    compute(QA, VA);                   // tile t4
    compute(QA + 8192, VA + 8192);     // tile t4+1
    __syncthreads();                   // drain: QB/VB ready
    if (s < 7) FSTAGE2(t4 + 4, QA, VA);
    compute(QB, VB);                   // tile t4+2
    compute(QB + 8192, VB + 8192);     // tile t4+3
    __syncthreads();
  }

  // ---- deferred l reduction over the 4 j-row-groups ----
  float inv[2];
#pragma unroll
  for (int ib = 0; ib < 2; ++ib) {
    lr[ib] += __shfl_xor(lr[ib], 16);
    lr[ib] += __shfl_xor(lr[ib], 32);
    inv[ib] = 1.0f / lr[ib];
  }

  // ---- epilogue: bf16 attn_t, swizzled k-major [b][i][c] ----
  unsigned* Pw = (unsigned*)(lds + w * 4096);  // 32 rows x 128B per wave
  const int kk = 4 * (l15 & 7);
#pragma unroll
  for (int ib = 0; ib < 2; ++ib)
#pragma unroll
    for (int mf = 0; mf < 4; ++mf) {
      uint2 pk;
      pk.x = cvtpk(accO[mf][ib][0] * inv[ib], accO[mf][ib][1] * inv[ib]);
      pk.y = cvtpk(accO[mf][ib][2] * inv[ib], accO[mf][ib][3] * inv[ib]);
      const int dwb = 8 * mf + 2 * g;
      *(uint2*)&Pw[(16 * ib + l15) * 32 + (dwb ^ kk)] = pk;
    }
  __syncthreads();
#pragma unroll
  for (int rep = 0; rep < 16; ++rep) {
    const int id = rep * 64 + lane;
    const int row = id >> 5, dw = id & 31;
    attn_t[((size_t)b * SEQ + i0 + 32 * w + row) * 256 + h * 32 + dw] =
        Pw[row * 32 + dw];
  }
#undef FSTAGE2
}

// ---------------------------------------------------------------------------
extern "C" void kernel_launch(void* const* d_in, const int* in_sizes, int n_in,
                              void* d_out, int out_size, void* d_ws, size_t ws_size,
                              hipStream_t stream) {
  const float* x      = (const float*)d_in[0];
  const float* w_qkv  = (const float*)d_in[1];
  const float* b_qkv  = (const float*)d_in[2];
  const float* w_dw   = (const float*)d_in[3];
  const float* b_dw   = (const float*)d_in[4];
  const float* w_po   = (const float*)d_in[5];
  const float* b_po   = (const float*)d_in[6];
  const float* temp   = (const float*)d_in[7];
  float* out = (float*)d_out;
  float* ws  = (float*)d_ws;

  // workspace layout (float units; qkv_pre/qkv bf16 inside their regions)
  ushort_t* qkv_pre_b = (ushort_t*)ws;            // 12.58M bf16 (fits region)
  ushort_t* qkvb = (ushort_t*)(ws + 12582912);    // 12.58M bf16 (q,k used)
  float* rq      = ws + 25165824;                 // 2048
  float* rk      = ws + 25167872;                 // 524,288
  unsigned* xbt  = (unsigned*)(ws + 25692160);    // 2M dwords (8MB)
  unsigned* wqb  = (unsigned*)(ws + 27789312);    // 384K dwords
  unsigned* wpb  = (unsigned*)(ws + 28182528);    // 128K dwords
  // xbt region reused after QKV GEMM:
  unsigned* vb     = (unsigned*)(ws + 25692160);  // 2M dwords (dwconv2 output)
  // qkv_pre region reused after dwconv2:
  unsigned* qt     = (unsigned*)(ws);             // 2M dwords
  unsigned* kt     = (unsigned*)(ws + 2097152);   // 2M dwords
  unsigned* attn_t = (unsigned*)(ws + 4194304);   // 2M dwords

  // 0) fused bf16 conversions (x transpose + weight prep, one launch)
  prep_inputs<<<3072, 256, 0, stream>>>(x, w_qkv, w_po, xbt, wqb, wpb);

  // 1) QKV pointwise conv (bf16 MFMA) -> bf16 qkv_pre
  gemm_mfma_bf16<true, 128>
      <<<dim3(SEQ / 128, C3 / 128, BATCH), 256, 0, stream>>>(
          (const ushort_t*)wqb, (const ushort_t*)xbt, b_qkv,
          (float*)qkv_pre_b, C3, SEQ);

  // 2) depthwise conv (bf16 in); v -> bf16 vb, q/k -> bf16 qkv; qnorm fused
  dwconv2<<<BATCH * C3, 256, 0, stream>>>(qkv_pre_b, w_dw, b_dw, qkvb, vb, rq);

  // 3) k norm (q norm fused into dwconv2)
  knorm_kernel<<<(BATCH * CH * SEQ) / 256, 256, 0, stream>>>(qkvb, rk);

  // 4) bf16 prep of qt / kt (coalesced transpose; qt rows permuted+swizzled)
  prep2<<<dim3(32, BATCH * HEADS, 2), 256, 0, stream>>>(
      qkvb, rq, rk, temp, qt, kt);

  // 5) MFMA flash attention -> bf16 attn_t (128-i blocks, paired j-tiles)
  flash_mfma<<<dim3(SEQ / 128, BATCH * HEADS), 256, 0, stream>>>(
      (const ushort_t*)qt, (const ushort_t*)kt, (const ushort_t*)vb, attn_t);

  // 6) output pointwise conv (bf16 MFMA, 64-row tiles: 512 blocks = 2/CU)
  gemm_mfma_bf16<false, 64>
      <<<dim3(SEQ / 128, DIM / 64, BATCH), 256, 0, stream>>>(
          (const ushort_t*)wpb, (const ushort_t*)attn_t, b_po, out, DIM, SEQ);
}